// Round 9
// baseline (380.083 us; speedup 1.0000x reference)
//
#include <hip/hip_runtime.h>
#include <hip/hip_fp16.h>

#define L_SEQ 4096
#define THR_GAP 0.08f
#define FIX_CAP 8192

typedef _Float16 f16x8 __attribute__((ext_vector_type(8)));
typedef _Float16 f16x4 __attribute__((ext_vector_type(4)));
typedef float f32x4 __attribute__((ext_vector_type(4)));

typedef __attribute__((address_space(3))) void lds_void;
typedef __attribute__((address_space(1))) void glob_void;
__device__ __forceinline__ void gload16(const _Float16* g, _Float16* l) {
  __builtin_amdgcn_global_load_lds((const glob_void*)g, (lds_void*)l, 16, 0, 0);
}

// ---------------- converts ----------------
__global__ __launch_bounds__(256)
void cvt_f16(const float* __restrict__ in, _Float16* __restrict__ out_) {
  int i = blockIdx.x * 256 + threadIdx.x;
  float4 v = ((const float4*)in)[i];
  f16x4 h;
  h[0] = (_Float16)v.x; h[1] = (_Float16)v.y;
  h[2] = (_Float16)v.z; h[3] = (_Float16)v.w;
  *(f16x4*)(out_ + (size_t)i * 4) = h;
}

__global__ __launch_bounds__(256)
void cvt_tr_f16(const float* __restrict__ W, _Float16* __restrict__ WT) {
  __shared__ _Float16 tile[32][33];
  const int bx = blockIdx.x * 32, by = blockIdx.y * 32;
  const int tx = threadIdx.x & 31, ty = threadIdx.x >> 5;
  #pragma unroll
  for (int i = ty; i < 32; i += 8)
    tile[i][tx] = (_Float16)W[(size_t)(by + i) * 1024 + bx + tx];
  __syncthreads();
  #pragma unroll
  for (int i = ty; i < 32; i += 8)
    WT[(size_t)(bx + i) * 1024 + by + tx] = tile[tx][i];
}

// ---------------- f16 MFMA GEMM, dbuf + counted vmcnt: C = A * BT^T ----------------
// MODE 0: C row-major f32; MODE 1: scatter f16 to [n][l][d]
template<int MODE>
__global__ __launch_bounds__(256)
void gemm_f16(const _Float16* __restrict__ A, const _Float16* __restrict__ BT,
              float* __restrict__ C, int M, int K, int Nn) {
  __shared__ _Float16 As[2][128 * 64];
  __shared__ _Float16 Bs[2][128 * 64];
  const int tid = threadIdx.x;
  const int lane = tid & 63, wid = tid >> 6;
  const int wr = wid >> 1, wc = wid & 1;
  const int f = blockIdx.x;
  const int u = (f & 7) * 64 + (f >> 3);
  const int row0 = (u >> 3) * 128, col0 = (u & 7) * 128;

  f32x4 acc[4][4];
  #pragma unroll
  for (int i = 0; i < 4; ++i)
    #pragma unroll
    for (int j = 0; j < 4; ++j)
      acc[i][j] = (f32x4){0.f, 0.f, 0.f, 0.f};

  const int srow = (lane >> 3);
  const int scol = ((lane & 7) ^ srow) * 8;
  const _Float16* ga = A + (size_t)(row0 + wid * 32 + srow) * K + scol;
  const _Float16* gb = BT + (size_t)(col0 + wid * 32 + srow) * K + scol;
  const int lbase = (wid * 32) * 64;
  const int fr = lane & 15, g = lane >> 4;

#define STAGE_F16(buf, k0) do {                                          \
    _Pragma("unroll")                                                    \
    for (int i_ = 0; i_ < 4; ++i_) {                                     \
      gload16(ga + (k0) + (size_t)i_ * 8 * K, &As[buf][lbase + i_ * 8 * 64]); \
      gload16(gb + (k0) + (size_t)i_ * 8 * K, &Bs[buf][lbase + i_ * 8 * 64]); \
    }                                                                    \
  } while (0)

  STAGE_F16(0, 0);

  const int NT = K / 64;
  for (int t = 0; t < NT; ++t) {
    const int cur = t & 1, nxt = cur ^ 1;
    if (t + 1 < NT) {
      STAGE_F16(nxt, (size_t)(t + 1) * 64);
      asm volatile("s_waitcnt vmcnt(8)" ::: "memory");
    } else {
      asm volatile("s_waitcnt vmcnt(0)" ::: "memory");
    }
    __builtin_amdgcn_s_barrier();
    __builtin_amdgcn_sched_barrier(0);

    f16x8 af[4][2], bf[4][2];
    #pragma unroll
    for (int fi = 0; fi < 4; ++fi) {
      const int ra = (wr * 64 + fi * 16 + fr) * 64;
      const int rb = (wc * 64 + fi * 16 + fr) * 64;
      #pragma unroll
      for (int ks = 0; ks < 2; ++ks) {
        const int ko = (ks * 32 + g * 8) ^ ((fr & 7) * 8);
        af[fi][ks] = *(const f16x8*)(&As[cur][ra + ko]);
        bf[fi][ks] = *(const f16x8*)(&Bs[cur][rb + ko]);
      }
    }
    #pragma unroll
    for (int ks = 0; ks < 2; ++ks)
      #pragma unroll
      for (int fi = 0; fi < 4; ++fi)
        #pragma unroll
        for (int fj = 0; fj < 4; ++fj)
          acc[fi][fj] = __builtin_amdgcn_mfma_f32_16x16x32_f16(
              af[fi][ks], bf[fj][ks], acc[fi][fj], 0, 0, 0);
    __builtin_amdgcn_s_barrier();
    __builtin_amdgcn_sched_barrier(0);
  }
#undef STAGE_F16

  _Float16* Ch = (_Float16*)C;
  #pragma unroll
  for (int fi = 0; fi < 4; ++fi) {
    #pragma unroll
    for (int fj = 0; fj < 4; ++fj) {
      const int col = col0 + wc * 64 + fj * 16 + fr;
      #pragma unroll
      for (int r = 0; r < 4; ++r) {
        const int row = row0 + wr * 64 + fi * 16 + g * 4 + r;
        if (MODE == 0) {
          C[(size_t)row * Nn + col] = acc[fi][fj][r];
        } else {
          int b = row >> 12, l = row & 4095;
          int h = col >> 6, d = col & 63;
          Ch[(((size_t)(b * 16 + h) * L_SEQ) + l) * 64 + d] = (_Float16)acc[fi][fj][r];
        }
      }
    }
  }
}

// ---------------- LSH hashing from f16 qk + per-(n,l) ambiguity flagging ----------------
__global__ __launch_bounds__(256)
void lsh_hash2(const _Float16* __restrict__ qkh, const float* __restrict__ rot,
               unsigned char* __restrict__ bucket,
               unsigned int* __restrict__ lists, unsigned int* __restrict__ cnt) {
  __shared__ float rots[4096];
  const int tid = threadIdx.x;
  for (int idx = tid; idx < 4096; idx += 256) rots[idx] = rot[idx];
  __syncthreads();
  const int n = blockIdx.y;
  const int l = blockIdx.x * 256 + tid;
  const f16x8* qp = (const f16x8*)(qkh + ((size_t)n * L_SEQ + l) * 64);
  float qr[64];
  #pragma unroll
  for (int t8 = 0; t8 < 8; ++t8) {
    f16x8 v = qp[t8];
    #pragma unroll
    for (int e = 0; e < 8; ++e) qr[t8 * 8 + e] = (float)v[e];
  }
  float gmin = 3.0e38f;
  #pragma unroll 1
  for (int hr = 0; hr < 2; ++hr) {
    float val[32];
    #pragma unroll
    for (int rb = 0; rb < 32; ++rb) val[rb] = 0.f;
    #pragma unroll
    for (int d = 0; d < 64; ++d) {
      float qd = qr[d];
      const float* rp = &rots[d * 64 + hr * 32];
      #pragma unroll
      for (int rb = 0; rb < 32; ++rb) val[rb] += qd * rp[rb];
    }
    float m1 = val[0]; int bi = 0;
    #pragma unroll
    for (int k = 1; k < 32; ++k) { if (val[k] > m1) { m1 = val[k]; bi = k; } }
    #pragma unroll
    for (int k = 0; k < 32; ++k) { float vn = -val[k]; if (vn > m1) { m1 = vn; bi = 32 + k; } }
    float m2 = -3.0e38f;
    #pragma unroll
    for (int k = 0; k < 32; ++k) { if (k != bi) m2 = fmaxf(m2, val[k]); }
    #pragma unroll
    for (int k = 0; k < 32; ++k) { if (32 + k != bi) m2 = fmaxf(m2, -val[k]); }
    bucket[((size_t)n * 2 + hr) * L_SEQ + l] = (unsigned char)bi;
    gmin = fminf(gmin, m1 - m2);
  }
  if (gmin < THR_GAP) {
    int h = n & 15;
    unsigned int pos = atomicAdd(&cnt[h], 1u);
    if (pos < FIX_CAP)
      lists[(size_t)h * FIX_CAP + pos] = ((unsigned int)n << 12) | (unsigned int)l;
  }
}

// ---------------- exact fp32 fixup: recompute qk row + all rotations ----------------
__global__ __launch_bounds__(256)
void lsh_fixup3(const float* __restrict__ x, const float* __restrict__ Wqk,
                const float* __restrict__ rot,
                const unsigned int* __restrict__ lists,
                const unsigned int* __restrict__ cnt,
                unsigned char* __restrict__ bucket) {
  __shared__ float rotL[4096];       // rot[d][nh][r]
  __shared__ float qkL[4][8][66];    // per-wave qk rows
  const int h = blockIdx.x & 15;
  const int bg = blockIdx.x >> 4;    // 0..15
  const int tid = threadIdx.x, lane = tid & 63, wv = tid >> 6;
  for (int i = tid; i < 4096; i += 256) rotL[i] = rot[i];
  __syncthreads();
  const unsigned int nfix = min(cnt[h], (unsigned int)FIX_CAP);
  const unsigned int* mylist = lists + (size_t)h * FIX_CAP;

  for (unsigned int base = ((unsigned int)(bg * 4 + wv)) * 8; base < nfix; base += 512) {
    int nn[8], ll[8];
    bool va[8];
    const float* xr[8];
    #pragma unroll
    for (int it = 0; it < 8; ++it) {
      unsigned int i = base + it;
      va[it] = (i < nfix);
      unsigned int ent = mylist[va[it] ? i : base];
      nn[it] = (int)(ent >> 12); ll[it] = (int)(ent & 4095);
      xr[it] = x + ((size_t)(nn[it] >> 4) * 4096 + ll[it]) * 1024;
    }
    // ---- phase A: exact fp32 qk row; lane owns output d = lane ----
    float acc[8];
    #pragma unroll
    for (int it = 0; it < 8; ++it) acc[it] = 0.f;
    const float* wp = Wqk + h * 64 + lane;
    for (int e4 = 0; e4 < 256; ++e4) {
      float w0 = wp[(size_t)(e4 * 4 + 0) * 1024];
      float w1 = wp[(size_t)(e4 * 4 + 1) * 1024];
      float w2 = wp[(size_t)(e4 * 4 + 2) * 1024];
      float w3 = wp[(size_t)(e4 * 4 + 3) * 1024];
      #pragma unroll
      for (int it = 0; it < 8; ++it) {
        float4 xv = *(const float4*)(xr[it] + e4 * 4);   // wave-uniform
        acc[it] += xv.x * w0 + xv.y * w1 + xv.z * w2 + xv.w * w3;
      }
    }
    // ---- phase B: rotations + argmax (both rounds), exact first-max ties ----
    #pragma unroll
    for (int it = 0; it < 8; ++it) qkL[wv][it][lane] = acc[it];
    const int p = lane >> 5, r = lane & 31;
    #pragma unroll 1
    for (int pp = 0; pp < 4; ++pp) {
      const int it = pp * 2 + p;
      float v0 = 0.f, v1 = 0.f;
      #pragma unroll
      for (int d = 0; d < 64; ++d) {
        float qv = qkL[wv][it][d];
        v0 += qv * rotL[d * 64 + r];
        v1 += qv * rotL[d * 64 + 32 + r];
      }
      #pragma unroll
      for (int nh = 0; nh < 2; ++nh) {
        float v = nh ? v1 : v0;
        float vneg = -v;
        float bv; int bi;
        if (vneg > v) { bv = vneg; bi = 32 + r; } else { bv = v; bi = r; }
        #pragma unroll
        for (int off = 1; off < 32; off <<= 1) {
          float ov = __shfl_xor(bv, off, 64);
          int oi = __shfl_xor(bi, off, 64);
          if (ov > bv || (ov == bv && oi < bi)) { bv = ov; bi = oi; }
        }
        if (r == 0 && va[it])
          bucket[((size_t)(nn[it] * 2 + nh)) * L_SEQ + ll[it]] = (unsigned char)bi;
      }
    }
  }
}

// ---------------- parallel stable counting sort per (n, round) ----------------
__global__ __launch_bounds__(256)
void lsh_sort(const unsigned char* __restrict__ bucket, unsigned int* __restrict__ st) {
  __shared__ unsigned short cnt[64][257];
  __shared__ unsigned int bstart[64];
  __shared__ unsigned char bkt[4096];
  const int nr = blockIdx.x;
  const int tid = threadIdx.x;
  const unsigned char* bsrc = bucket + (size_t)nr * L_SEQ;
  for (int i = tid; i < 1024; i += 256)
    ((unsigned int*)bkt)[i] = ((const unsigned int*)bsrc)[i];
  #pragma unroll
  for (int b = 0; b < 64; ++b) cnt[b][tid] = 0;
  __syncthreads();
  uint4 wv = ((const uint4*)bkt)[tid];
  unsigned int wsg[4] = {wv.x, wv.y, wv.z, wv.w};
  #pragma unroll
  for (int k = 0; k < 16; ++k) {
    int b = (wsg[k >> 2] >> ((k & 3) * 8)) & 63;
    cnt[b][tid]++;
  }
  __syncthreads();
  if (tid < 64) {
    const int b = tid;
    unsigned int run = 0;
    for (int t = 0; t < 256; ++t) {
      unsigned int c = cnt[b][t];
      cnt[b][t] = (unsigned short)run;
      run += c;
    }
    unsigned int incl = run;
    #pragma unroll
    for (int off = 1; off < 64; off <<= 1) {
      unsigned int up = (unsigned int)__shfl_up((int)incl, off);
      if (tid >= off) incl += up;
    }
    bstart[b] = incl - run;
  }
  __syncthreads();
  const int n = nr >> 1, r = nr & 1;
  unsigned int* dst = st + (size_t)n * 8192 + (size_t)r * 4096;
  #pragma unroll
  for (int k = 0; k < 16; ++k) {
    int b = (wsg[k >> 2] >> ((k & 3) * 8)) & 63;
    unsigned int idx = bstart[b] + cnt[b][tid];
    cnt[b][tid]++;
    dst[idx] = (unsigned int)(tid * 16 + k);
  }
}

// ---------------- MFMA chunked local attention (f16 qk gather) ----------------
__global__ __launch_bounds__(256)
void lsh_attn_mfma(const _Float16* __restrict__ qkh, const _Float16* __restrict__ vh,
                   const unsigned int* __restrict__ st,
                   _Float16* __restrict__ o, float* __restrict__ logits) {
  __shared__ _Float16 Kl[128 * 64];
  __shared__ _Float16 Vt[64 * 128];
  __shared__ _Float16 Pl[64 * 128];
  __shared__ float rsqs[128];
  __shared__ float partial[256];
  __shared__ int posl[128];

  const int tid = threadIdx.x;
  const int lane = tid & 63, wid = tid >> 6;
  const int fr = lane & 15, g = lane >> 4;
  const int c = blockIdx.x, n = blockIdx.y;
  const int cprev = (c + 127) & 127;

  if (tid < 128) {
    int p = (tid < 64) ? (c * 64 + tid) : (cprev * 64 + (tid - 64));
    posl[tid] = (int)st[(size_t)n * 8192 + p];
  }
  __syncthreads();

  {
    const int j = tid >> 1, h = tid & 1;
    const int gpos = posl[j];
    const f16x8* srcK = (const f16x8*)(qkh + ((size_t)n * L_SEQ + gpos) * 64 + h * 32);
    const f16x8* srcV = (const f16x8*)(vh + ((size_t)n * L_SEQ + gpos) * 64 + h * 32);
    float ss = 0.f;
    #pragma unroll
    for (int i = 0; i < 4; ++i) {
      f16x8 kv = srcK[i];
      f16x8 vv4 = srcV[i];
      #pragma unroll
      for (int e = 0; e < 8; ++e) {
        float xv = (float)kv[e];
        ss += xv * xv;
        int d = h * 32 + i * 8 + e;
        Vt[d * 128 + (j ^ ((d & 7) << 3))] = vv4[e];
      }
      int ch = h * 4 + i;
      *(f16x8*)(&Kl[j * 64 + ((ch ^ (j & 7)) * 8)]) = kv;
    }
    partial[tid] = ss;
  }
  __syncthreads();
  if (tid < 128)
    rsqs[tid] = rsqrtf(fmaxf(partial[tid * 2] + partial[tid * 2 + 1], 1e-12f));
  __syncthreads();

  const int q0 = wid * 16;
  f32x4 acc[8];
  #pragma unroll
  for (int t = 0; t < 8; ++t) acc[t] = (f32x4){0.f, 0.f, 0.f, 0.f};
  f16x8 aq[2];
  #pragma unroll
  for (int ks = 0; ks < 2; ++ks)
    aq[ks] = *(const f16x8*)&Kl[(q0 + fr) * 64 + (((ks * 4 + g) ^ (fr & 7)) * 8)];
  #pragma unroll
  for (int t = 0; t < 8; ++t) {
    #pragma unroll
    for (int ks = 0; ks < 2; ++ks) {
      f16x8 bk = *(const f16x8*)&Kl[(t * 16 + fr) * 64 + (((ks * 4 + g) ^ (fr & 7)) * 8)];
      acc[t] = __builtin_amdgcn_mfma_f32_16x16x32_f16(aq[ks], bk, acc[t], 0, 0, 0);
    }
  }

  float sc[8][4];
  int pq[4];
  #pragma unroll
  for (int r = 0; r < 4; ++r) pq[r] = posl[q0 + g * 4 + r];
  #pragma unroll
  for (int t = 0; t < 8; ++t) {
    float rs = rsqs[t * 16 + fr] * 0.125f;
    int pk = posl[t * 16 + fr];
    #pragma unroll
    for (int r = 0; r < 4; ++r) {
      float v_ = acc[t][r] * rs;
      if (pq[r] == pk) v_ += -1e5f;
      sc[t][r] = v_;
    }
  }
  float lsef[4];
  #pragma unroll
  for (int r = 0; r < 4; ++r) {
    float m = sc[0][r];
    #pragma unroll
    for (int t = 1; t < 8; ++t) m = fmaxf(m, sc[t][r]);
    #pragma unroll
    for (int off = 1; off < 16; off <<= 1) m = fmaxf(m, __shfl_xor(m, off, 64));
    float s = 0.f;
    #pragma unroll
    for (int t = 0; t < 8; ++t) { float e = __expf(sc[t][r] - m); sc[t][r] = e; s += e; }
    #pragma unroll
    for (int off = 1; off < 16; off <<= 1) s += __shfl_xor(s, off, 64);
    lsef[r] = m + __logf(s);
    float f = 1.0f / s;
    #pragma unroll
    for (int t = 0; t < 8; ++t) sc[t][r] *= f;
  }

  #pragma unroll
  for (int t = 0; t < 8; ++t)
    #pragma unroll
    for (int r = 0; r < 4; ++r) {
      int q = q0 + g * 4 + r;
      Pl[q * 128 + ((t * 16 + fr) ^ ((q & 7) << 3))] = (_Float16)sc[t][r];
    }
  const int rr = c >> 6;
  if (fr == 0) {
    #pragma unroll
    for (int r = 0; r < 4; ++r) {
      int q = q0 + g * 4 + r;
      logits[((size_t)n * 2 + rr) * L_SEQ + posl[q]] = lsef[r];
    }
  }

  f32x4 acc2[4];
  #pragma unroll
  for (int td = 0; td < 4; ++td) acc2[td] = (f32x4){0.f, 0.f, 0.f, 0.f};
  #pragma unroll
  for (int s = 0; s < 4; ++s) {
    f16x8 ap = *(const f16x8*)&Pl[(q0 + fr) * 128 + (((s * 4 + g) ^ (fr & 7)) * 8)];
    #pragma unroll
    for (int td = 0; td < 4; ++td) {
      f16x8 bv = *(const f16x8*)&Vt[(td * 16 + fr) * 128 + (((s * 4 + g) ^ (fr & 7)) * 8)];
      acc2[td] = __builtin_amdgcn_mfma_f32_16x16x32_f16(ap, bv, acc2[td], 0, 0, 0);
    }
  }
  #pragma unroll
  for (int r = 0; r < 4; ++r) {
    int q = q0 + g * 4 + r;
    size_t base = (((size_t)n * 2 + rr) * L_SEQ + posl[q]) * 64;
    #pragma unroll
    for (int td = 0; td < 4; ++td)
      o[base + td * 16 + fr] = (_Float16)acc2[td][r];
  }
}

// ---------------- combine hash rounds -> f16 att [8192][1024] ----------------
__global__ __launch_bounds__(256)
void lsh_combine(const __half* __restrict__ o, const float* __restrict__ logits,
                 _Float16* __restrict__ attf) {
  size_t gid = (size_t)blockIdx.x * 256 + threadIdx.x;
  int q4 = (int)(gid & 15);
  size_t nl = gid >> 4;
  int n = (int)(nl >> 12), l = (int)(nl & 4095);
  float l0 = logits[((size_t)n * 2 + 0) * L_SEQ + l];
  float l1 = logits[((size_t)n * 2 + 1) * L_SEQ + l];
  float m = fmaxf(l0, l1);
  float e0 = __expf(l0 - m), e1 = __expf(l1 - m);
  float inv = 1.0f / (e0 + e1);
  float w0 = e0 * inv, w1 = e1 * inv;
  const __half2* r0 = (const __half2*)(o + (((size_t)n * 2 + 0) * L_SEQ + l) * 64) + q4 * 2;
  const __half2* r1 = (const __half2*)(o + (((size_t)n * 2 + 1) * L_SEQ + l) * 64) + q4 * 2;
  float2 a0 = __half22float2(r0[0]), a1 = __half22float2(r0[1]);
  float2 b0 = __half22float2(r1[0]), b1 = __half22float2(r1[1]);
  f16x4 res;
  res[0] = (_Float16)(w0 * a0.x + w1 * b0.x);
  res[1] = (_Float16)(w0 * a0.y + w1 * b0.y);
  res[2] = (_Float16)(w0 * a1.x + w1 * b1.x);
  res[3] = (_Float16)(w0 * a1.y + w1 * b1.y);
  int bb = n >> 4, h = n & 15;
  *(f16x4*)(attf + ((size_t)bb * L_SEQ + l) * 1024 + h * 64 + q4 * 4) = res;
}

extern "C" void kernel_launch(void* const* d_in, const int* in_sizes, int n_in,
                              void* d_out, int out_size, void* d_ws, size_t ws_size,
                              hipStream_t stream) {
  const float* x   = (const float*)d_in[0];
  const float* Wqk = (const float*)d_in[2];
  const float* Wv  = (const float*)d_in[3];
  const float* Wo  = (const float*)d_in[4];
  const float* rot = (const float*)d_in[5];
  float* out = (float*)d_out;
  char* ws = (char*)d_ws;

  _Float16*     qkh    = (_Float16*)(ws + 0);                 // 16 MB
  _Float16*     vh     = (_Float16*)(ws + 16777216ull);       // 16 MB
  _Float16*     xh     = (_Float16*)(ws + 33554432ull);       // 16 MB (dead after gemms)
  _Float16*     attf   = (_Float16*)(ws + 33554432ull);       // overlays xh
  _Float16*     o      = (_Float16*)(ws + 50331648ull);       // 32 MB (attn output)
  // pre-attn scratch overlaying the o region:
  unsigned int* lists  = (unsigned int*)(ws + 52428800ull);   // 512 KB (16 lists)
  unsigned int* cntp   = (unsigned int*)(ws + 53477376ull);   // 64 B
  float*        logits = (float*)(ws + 83886080ull);          // 1 MB
  unsigned int* st     = (unsigned int*)(ws + 84934656ull);   // 1 MB
  unsigned char* bucket = (unsigned char*)(ws + 85983232ull); // 256 KB
  _Float16*     WqkT   = (_Float16*)(ws + 86245376ull);       // 2 MB
  _Float16*     WvT    = (_Float16*)(ws + 88342528ull);       // 2 MB
  _Float16*     WoT    = (_Float16*)(ws + 90439680ull);       // 2 MB

  dim3 gb(256);
  dim3 gemmGrid(512);

  hipMemsetAsync(cntp, 0, 16 * sizeof(unsigned int), stream);
  cvt_f16<<<dim3(8192), gb, 0, stream>>>(x, xh);
  cvt_tr_f16<<<dim3(32, 32), gb, 0, stream>>>(Wqk, WqkT);
  cvt_tr_f16<<<dim3(32, 32), gb, 0, stream>>>(Wv, WvT);
  cvt_tr_f16<<<dim3(32, 32), gb, 0, stream>>>(Wo, WoT);

  gemm_f16<1><<<gemmGrid, gb, 0, stream>>>(xh, WqkT, (float*)qkh, 8192, 1024, 1024);
  gemm_f16<1><<<gemmGrid, gb, 0, stream>>>(xh, WvT, (float*)vh, 8192, 1024, 1024);

  lsh_hash2<<<dim3(16, 32), gb, 0, stream>>>(qkh, rot, bucket, lists, cntp);
  lsh_fixup3<<<dim3(256), gb, 0, stream>>>(x, Wqk, rot, lists, cntp, bucket);
  lsh_sort<<<dim3(64), gb, 0, stream>>>(bucket, st);
  lsh_attn_mfma<<<dim3(128, 32), gb, 0, stream>>>(qkh, vh, st, o, logits);
  lsh_combine<<<dim3(8192), gb, 0, stream>>>((const __half*)o, logits, attf);

  gemm_f16<0><<<gemmGrid, gb, 0, stream>>>(attf, WoT, out, 8192, 1024, 1024);
}

// Round 10
// 295.535 us; speedup vs baseline: 1.2861x; 1.2861x over previous
//
#include <hip/hip_runtime.h>
#include <hip/hip_fp16.h>

#define L_SEQ 4096
#define THR_GAP 0.08f
#define FIX_CAP 8192

typedef _Float16 f16x8 __attribute__((ext_vector_type(8)));
typedef _Float16 f16x4 __attribute__((ext_vector_type(4)));
typedef float f32x4 __attribute__((ext_vector_type(4)));

typedef __attribute__((address_space(3))) void lds_void;
typedef __attribute__((address_space(1))) void glob_void;
__device__ __forceinline__ void gload16(const _Float16* g, _Float16* l) {
  __builtin_amdgcn_global_load_lds((const glob_void*)g, (lds_void*)l, 16, 0, 0);
}

// ---------------- converts ----------------
__global__ __launch_bounds__(256)
void cvt_f16(const float* __restrict__ in, _Float16* __restrict__ out_) {
  int i = blockIdx.x * 256 + threadIdx.x;
  float4 v = ((const float4*)in)[i];
  f16x4 h;
  h[0] = (_Float16)v.x; h[1] = (_Float16)v.y;
  h[2] = (_Float16)v.z; h[3] = (_Float16)v.w;
  *(f16x4*)(out_ + (size_t)i * 4) = h;
}

__global__ __launch_bounds__(256)
void cvt_tr_f16(const float* __restrict__ W, _Float16* __restrict__ WT) {
  __shared__ _Float16 tile[32][33];
  const int bx = blockIdx.x * 32, by = blockIdx.y * 32;
  const int tx = threadIdx.x & 31, ty = threadIdx.x >> 5;
  #pragma unroll
  for (int i = ty; i < 32; i += 8)
    tile[i][tx] = (_Float16)W[(size_t)(by + i) * 1024 + bx + tx];
  __syncthreads();
  #pragma unroll
  for (int i = ty; i < 32; i += 8)
    WT[(size_t)(bx + i) * 1024 + by + tx] = tile[tx][i];
}

// ---------------- f16 MFMA GEMM, dbuf + counted vmcnt: C = A * BT^T ----------------
// MODE 0: C row-major f32; MODE 1: scatter f16 to [n][l][d]
template<int MODE>
__global__ __launch_bounds__(256)
void gemm_f16(const _Float16* __restrict__ A, const _Float16* __restrict__ BT,
              float* __restrict__ C, int M, int K, int Nn) {
  __shared__ _Float16 As[2][128 * 64];
  __shared__ _Float16 Bs[2][128 * 64];
  const int tid = threadIdx.x;
  const int lane = tid & 63, wid = tid >> 6;
  const int wr = wid >> 1, wc = wid & 1;
  const int f = blockIdx.x;
  const int u = (f & 7) * 64 + (f >> 3);
  const int row0 = (u >> 3) * 128, col0 = (u & 7) * 128;

  f32x4 acc[4][4];
  #pragma unroll
  for (int i = 0; i < 4; ++i)
    #pragma unroll
    for (int j = 0; j < 4; ++j)
      acc[i][j] = (f32x4){0.f, 0.f, 0.f, 0.f};

  const int srow = (lane >> 3);
  const int scol = ((lane & 7) ^ srow) * 8;
  const _Float16* ga = A + (size_t)(row0 + wid * 32 + srow) * K + scol;
  const _Float16* gb = BT + (size_t)(col0 + wid * 32 + srow) * K + scol;
  const int lbase = (wid * 32) * 64;
  const int fr = lane & 15, g = lane >> 4;

#define STAGE_F16(buf, k0) do {                                          \
    _Pragma("unroll")                                                    \
    for (int i_ = 0; i_ < 4; ++i_) {                                     \
      gload16(ga + (k0) + (size_t)i_ * 8 * K, &As[buf][lbase + i_ * 8 * 64]); \
      gload16(gb + (k0) + (size_t)i_ * 8 * K, &Bs[buf][lbase + i_ * 8 * 64]); \
    }                                                                    \
  } while (0)

  STAGE_F16(0, 0);

  const int NT = K / 64;
  for (int t = 0; t < NT; ++t) {
    const int cur = t & 1, nxt = cur ^ 1;
    if (t + 1 < NT) {
      STAGE_F16(nxt, (size_t)(t + 1) * 64);
      asm volatile("s_waitcnt vmcnt(8)" ::: "memory");
    } else {
      asm volatile("s_waitcnt vmcnt(0)" ::: "memory");
    }
    __builtin_amdgcn_s_barrier();
    __builtin_amdgcn_sched_barrier(0);

    f16x8 af[4][2], bf[4][2];
    #pragma unroll
    for (int fi = 0; fi < 4; ++fi) {
      const int ra = (wr * 64 + fi * 16 + fr) * 64;
      const int rb = (wc * 64 + fi * 16 + fr) * 64;
      #pragma unroll
      for (int ks = 0; ks < 2; ++ks) {
        const int ko = (ks * 32 + g * 8) ^ ((fr & 7) * 8);
        af[fi][ks] = *(const f16x8*)(&As[cur][ra + ko]);
        bf[fi][ks] = *(const f16x8*)(&Bs[cur][rb + ko]);
      }
    }
    #pragma unroll
    for (int ks = 0; ks < 2; ++ks)
      #pragma unroll
      for (int fi = 0; fi < 4; ++fi)
        #pragma unroll
        for (int fj = 0; fj < 4; ++fj)
          acc[fi][fj] = __builtin_amdgcn_mfma_f32_16x16x32_f16(
              af[fi][ks], bf[fj][ks], acc[fi][fj], 0, 0, 0);
    __builtin_amdgcn_s_barrier();
    __builtin_amdgcn_sched_barrier(0);
  }
#undef STAGE_F16

  _Float16* Ch = (_Float16*)C;
  #pragma unroll
  for (int fi = 0; fi < 4; ++fi) {
    #pragma unroll
    for (int fj = 0; fj < 4; ++fj) {
      const int col = col0 + wc * 64 + fj * 16 + fr;
      #pragma unroll
      for (int r = 0; r < 4; ++r) {
        const int row = row0 + wr * 64 + fi * 16 + g * 4 + r;
        if (MODE == 0) {
          C[(size_t)row * Nn + col] = acc[fi][fj][r];
        } else {
          int b = row >> 12, l = row & 4095;
          int h = col >> 6, d = col & 63;
          Ch[(((size_t)(b * 16 + h) * L_SEQ) + l) * 64 + d] = (_Float16)acc[fi][fj][r];
        }
      }
    }
  }
}

// ---------------- LSH hashing from f16 qk + per-(n,l) ambiguity flagging ----------------
__global__ __launch_bounds__(256)
void lsh_hash2(const _Float16* __restrict__ qkh, const float* __restrict__ rot,
               unsigned char* __restrict__ bucket,
               unsigned int* __restrict__ lists, unsigned int* __restrict__ cnt) {
  __shared__ float rots[4096];
  const int tid = threadIdx.x;
  for (int idx = tid; idx < 4096; idx += 256) rots[idx] = rot[idx];
  __syncthreads();
  const int n = blockIdx.y;
  const int l = blockIdx.x * 256 + tid;
  const f16x8* qp = (const f16x8*)(qkh + ((size_t)n * L_SEQ + l) * 64);
  float qr[64];
  #pragma unroll
  for (int t8 = 0; t8 < 8; ++t8) {
    f16x8 v = qp[t8];
    #pragma unroll
    for (int e = 0; e < 8; ++e) qr[t8 * 8 + e] = (float)v[e];
  }
  float gmin = 3.0e38f;
  #pragma unroll 1
  for (int hr = 0; hr < 2; ++hr) {
    float val[32];
    #pragma unroll
    for (int rb = 0; rb < 32; ++rb) val[rb] = 0.f;
    #pragma unroll
    for (int d = 0; d < 64; ++d) {
      float qd = qr[d];
      const float* rp = &rots[d * 64 + hr * 32];
      #pragma unroll
      for (int rb = 0; rb < 32; ++rb) val[rb] += qd * rp[rb];
    }
    float m1 = val[0]; int bi = 0;
    #pragma unroll
    for (int k = 1; k < 32; ++k) { if (val[k] > m1) { m1 = val[k]; bi = k; } }
    #pragma unroll
    for (int k = 0; k < 32; ++k) { float vn = -val[k]; if (vn > m1) { m1 = vn; bi = 32 + k; } }
    float m2 = -3.0e38f;
    #pragma unroll
    for (int k = 0; k < 32; ++k) { if (k != bi) m2 = fmaxf(m2, val[k]); }
    #pragma unroll
    for (int k = 0; k < 32; ++k) { if (32 + k != bi) m2 = fmaxf(m2, -val[k]); }
    bucket[((size_t)n * 2 + hr) * L_SEQ + l] = (unsigned char)bi;
    gmin = fminf(gmin, m1 - m2);
  }
  if (gmin < THR_GAP) {
    int h = n & 15;
    unsigned int pos = atomicAdd(&cnt[h], 1u);
    if (pos < FIX_CAP)
      lists[(size_t)h * FIX_CAP + pos] = ((unsigned int)n << 12) | (unsigned int)l;
  }
}

// ---------------- exact fp32 fixup: one wave per flagged token ----------------
__global__ __launch_bounds__(256)
void lsh_fixup4(const float* __restrict__ x, const float* __restrict__ Wqk,
                const float* __restrict__ rot,
                const unsigned int* __restrict__ lists,
                const unsigned int* __restrict__ cnt,
                unsigned char* __restrict__ bucket) {
  __shared__ float rotL[4096];      // rot[d][nh*32+r]
  __shared__ float xL[4][1024];     // per-wave staged x row
  __shared__ float qkL[4][64];      // per-wave qk row
  const int h = blockIdx.x & 15;
  const int bg = blockIdx.x >> 4;   // 0..31
  const int tid = threadIdx.x, lane = tid & 63, wv = tid >> 6;
  for (int i = tid; i < 4096; i += 256) rotL[i] = rot[i];
  __syncthreads();
  const unsigned int nfix = min(cnt[h], (unsigned int)FIX_CAP);
  const unsigned int* mylist = lists + (size_t)h * FIX_CAP;

  for (unsigned int i = (unsigned int)(bg * 4 + wv); i < nfix; i += 128) {
    const unsigned int ent = mylist[i];
    const int nn = (int)(ent >> 12), ll = (int)(ent & 4095);

    // stage x row (coalesced float4)
    const float4* xr = (const float4*)(x + ((size_t)(nn >> 4) * 4096 + ll) * 1024);
    float4* xl4 = (float4*)&xL[wv][0];
    #pragma unroll
    for (int k = 0; k < 4; ++k) xl4[lane + k * 64] = xr[lane + k * 64];
    asm volatile("s_waitcnt vmcnt(0) lgkmcnt(0)" ::: "memory");

    // ---- phase A: exact fp32 qk row, lane = output d; sequential e order ----
    float acc = 0.f;
    const float* wp = Wqk + h * 64 + lane;
    #pragma unroll 16
    for (int e = 0; e < 1024; ++e)
      acc += xL[wv][e] * wp[(size_t)e * 1024];
    qkL[wv][lane] = acc;
    asm volatile("s_waitcnt lgkmcnt(0)" ::: "memory");
    __builtin_amdgcn_sched_barrier(0);

    // ---- phase B: rotations, lane = hr*32 + r ----
    float v = 0.f;
    #pragma unroll 8
    for (int d = 0; d < 64; ++d)
      v += qkL[wv][d] * rotL[d * 64 + lane];
    float bv; int bi;
    const int r = lane & 31;
    float vneg = -v;
    if (vneg > v) { bv = vneg; bi = 32 + r; } else { bv = v; bi = r; }
    #pragma unroll
    for (int off = 1; off < 32; off <<= 1) {
      float ov = __shfl_xor(bv, off, 64);
      int oi = __shfl_xor(bi, off, 64);
      if (ov > bv || (ov == bv && oi < bi)) { bv = ov; bi = oi; }
    }
    if (r == 0) {
      int hr = lane >> 5;
      bucket[((size_t)(nn * 2 + hr)) * L_SEQ + ll] = (unsigned char)bi;
    }
  }
}

// ---------------- parallel stable counting sort per (n, round) ----------------
__global__ __launch_bounds__(256)
void lsh_sort(const unsigned char* __restrict__ bucket, unsigned int* __restrict__ st) {
  __shared__ unsigned short cnt[64][257];
  __shared__ unsigned int bstart[64];
  __shared__ unsigned char bkt[4096];
  const int nr = blockIdx.x;
  const int tid = threadIdx.x;
  const unsigned char* bsrc = bucket + (size_t)nr * L_SEQ;
  for (int i = tid; i < 1024; i += 256)
    ((unsigned int*)bkt)[i] = ((const unsigned int*)bsrc)[i];
  #pragma unroll
  for (int b = 0; b < 64; ++b) cnt[b][tid] = 0;
  __syncthreads();
  uint4 wv = ((const uint4*)bkt)[tid];
  unsigned int wsg[4] = {wv.x, wv.y, wv.z, wv.w};
  #pragma unroll
  for (int k = 0; k < 16; ++k) {
    int b = (wsg[k >> 2] >> ((k & 3) * 8)) & 63;
    cnt[b][tid]++;
  }
  __syncthreads();
  if (tid < 64) {
    const int b = tid;
    unsigned int run = 0;
    for (int t = 0; t < 256; ++t) {
      unsigned int c = cnt[b][t];
      cnt[b][t] = (unsigned short)run;
      run += c;
    }
    unsigned int incl = run;
    #pragma unroll
    for (int off = 1; off < 64; off <<= 1) {
      unsigned int up = (unsigned int)__shfl_up((int)incl, off);
      if (tid >= off) incl += up;
    }
    bstart[b] = incl - run;
  }
  __syncthreads();
  const int n = nr >> 1, r = nr & 1;
  unsigned int* dst = st + (size_t)n * 8192 + (size_t)r * 4096;
  #pragma unroll
  for (int k = 0; k < 16; ++k) {
    int b = (wsg[k >> 2] >> ((k & 3) * 8)) & 63;
    unsigned int idx = bstart[b] + cnt[b][tid];
    cnt[b][tid]++;
    dst[idx] = (unsigned int)(tid * 16 + k);
  }
}

// ---------------- MFMA chunked local attention (f16 qk gather) ----------------
__global__ __launch_bounds__(256)
void lsh_attn_mfma(const _Float16* __restrict__ qkh, const _Float16* __restrict__ vh,
                   const unsigned int* __restrict__ st,
                   _Float16* __restrict__ o, float* __restrict__ logits) {
  __shared__ _Float16 Kl[128 * 64];
  __shared__ _Float16 Vt[64 * 128];
  __shared__ _Float16 Pl[64 * 128];
  __shared__ float rsqs[128];
  __shared__ float partial[256];
  __shared__ int posl[128];

  const int tid = threadIdx.x;
  const int lane = tid & 63, wid = tid >> 6;
  const int fr = lane & 15, g = lane >> 4;
  const int c = blockIdx.x, n = blockIdx.y;
  const int cprev = (c + 127) & 127;

  if (tid < 128) {
    int p = (tid < 64) ? (c * 64 + tid) : (cprev * 64 + (tid - 64));
    posl[tid] = (int)st[(size_t)n * 8192 + p];
  }
  __syncthreads();

  {
    const int j = tid >> 1, h = tid & 1;
    const int gpos = posl[j];
    const f16x8* srcK = (const f16x8*)(qkh + ((size_t)n * L_SEQ + gpos) * 64 + h * 32);
    const f16x8* srcV = (const f16x8*)(vh + ((size_t)n * L_SEQ + gpos) * 64 + h * 32);
    float ss = 0.f;
    #pragma unroll
    for (int i = 0; i < 4; ++i) {
      f16x8 kv = srcK[i];
      f16x8 vv4 = srcV[i];
      #pragma unroll
      for (int e = 0; e < 8; ++e) {
        float xv = (float)kv[e];
        ss += xv * xv;
        int d = h * 32 + i * 8 + e;
        Vt[d * 128 + (j ^ ((d & 7) << 3))] = vv4[e];
      }
      int ch = h * 4 + i;
      *(f16x8*)(&Kl[j * 64 + ((ch ^ (j & 7)) * 8)]) = kv;
    }
    partial[tid] = ss;
  }
  __syncthreads();
  if (tid < 128)
    rsqs[tid] = rsqrtf(fmaxf(partial[tid * 2] + partial[tid * 2 + 1], 1e-12f));
  __syncthreads();

  const int q0 = wid * 16;
  f32x4 acc[8];
  #pragma unroll
  for (int t = 0; t < 8; ++t) acc[t] = (f32x4){0.f, 0.f, 0.f, 0.f};
  f16x8 aq[2];
  #pragma unroll
  for (int ks = 0; ks < 2; ++ks)
    aq[ks] = *(const f16x8*)&Kl[(q0 + fr) * 64 + (((ks * 4 + g) ^ (fr & 7)) * 8)];
  #pragma unroll
  for (int t = 0; t < 8; ++t) {
    #pragma unroll
    for (int ks = 0; ks < 2; ++ks) {
      f16x8 bk = *(const f16x8*)&Kl[(t * 16 + fr) * 64 + (((ks * 4 + g) ^ (fr & 7)) * 8)];
      acc[t] = __builtin_amdgcn_mfma_f32_16x16x32_f16(aq[ks], bk, acc[t], 0, 0, 0);
    }
  }

  float sc[8][4];
  int pq[4];
  #pragma unroll
  for (int r = 0; r < 4; ++r) pq[r] = posl[q0 + g * 4 + r];
  #pragma unroll
  for (int t = 0; t < 8; ++t) {
    float rs = rsqs[t * 16 + fr] * 0.125f;
    int pk = posl[t * 16 + fr];
    #pragma unroll
    for (int r = 0; r < 4; ++r) {
      float v_ = acc[t][r] * rs;
      if (pq[r] == pk) v_ += -1e5f;
      sc[t][r] = v_;
    }
  }
  float lsef[4];
  #pragma unroll
  for (int r = 0; r < 4; ++r) {
    float m = sc[0][r];
    #pragma unroll
    for (int t = 1; t < 8; ++t) m = fmaxf(m, sc[t][r]);
    #pragma unroll
    for (int off = 1; off < 16; off <<= 1) m = fmaxf(m, __shfl_xor(m, off, 64));
    float s = 0.f;
    #pragma unroll
    for (int t = 0; t < 8; ++t) { float e = __expf(sc[t][r] - m); sc[t][r] = e; s += e; }
    #pragma unroll
    for (int off = 1; off < 16; off <<= 1) s += __shfl_xor(s, off, 64);
    lsef[r] = m + __logf(s);
    float f = 1.0f / s;
    #pragma unroll
    for (int t = 0; t < 8; ++t) sc[t][r] *= f;
  }

  #pragma unroll
  for (int t = 0; t < 8; ++t)
    #pragma unroll
    for (int r = 0; r < 4; ++r) {
      int q = q0 + g * 4 + r;
      Pl[q * 128 + ((t * 16 + fr) ^ ((q & 7) << 3))] = (_Float16)sc[t][r];
    }
  const int rr = c >> 6;
  if (fr == 0) {
    #pragma unroll
    for (int r = 0; r < 4; ++r) {
      int q = q0 + g * 4 + r;
      logits[((size_t)n * 2 + rr) * L_SEQ + posl[q]] = lsef[r];
    }
  }

  f32x4 acc2[4];
  #pragma unroll
  for (int td = 0; td < 4; ++td) acc2[td] = (f32x4){0.f, 0.f, 0.f, 0.f};
  #pragma unroll
  for (int s = 0; s < 4; ++s) {
    f16x8 ap = *(const f16x8*)&Pl[(q0 + fr) * 128 + (((s * 4 + g) ^ (fr & 7)) * 8)];
    #pragma unroll
    for (int td = 0; td < 4; ++td) {
      f16x8 bv = *(const f16x8*)&Vt[(td * 16 + fr) * 128 + (((s * 4 + g) ^ (fr & 7)) * 8)];
      acc2[td] = __builtin_amdgcn_mfma_f32_16x16x32_f16(ap, bv, acc2[td], 0, 0, 0);
    }
  }
  #pragma unroll
  for (int r = 0; r < 4; ++r) {
    int q = q0 + g * 4 + r;
    size_t base = (((size_t)n * 2 + rr) * L_SEQ + posl[q]) * 64;
    #pragma unroll
    for (int td = 0; td < 4; ++td)
      o[base + td * 16 + fr] = (_Float16)acc2[td][r];
  }
}

// ---------------- combine hash rounds -> f16 att [8192][1024] ----------------
__global__ __launch_bounds__(256)
void lsh_combine(const __half* __restrict__ o, const float* __restrict__ logits,
                 _Float16* __restrict__ attf) {
  size_t gid = (size_t)blockIdx.x * 256 + threadIdx.x;
  int q4 = (int)(gid & 15);
  size_t nl = gid >> 4;
  int n = (int)(nl >> 12), l = (int)(nl & 4095);
  float l0 = logits[((size_t)n * 2 + 0) * L_SEQ + l];
  float l1 = logits[((size_t)n * 2 + 1) * L_SEQ + l];
  float m = fmaxf(l0, l1);
  float e0 = __expf(l0 - m), e1 = __expf(l1 - m);
  float inv = 1.0f / (e0 + e1);
  float w0 = e0 * inv, w1 = e1 * inv;
  const __half2* r0 = (const __half2*)(o + (((size_t)n * 2 + 0) * L_SEQ + l) * 64) + q4 * 2;
  const __half2* r1 = (const __half2*)(o + (((size_t)n * 2 + 1) * L_SEQ + l) * 64) + q4 * 2;
  float2 a0 = __half22float2(r0[0]), a1 = __half22float2(r0[1]);
  float2 b0 = __half22float2(r1[0]), b1 = __half22float2(r1[1]);
  f16x4 res;
  res[0] = (_Float16)(w0 * a0.x + w1 * b0.x);
  res[1] = (_Float16)(w0 * a0.y + w1 * b0.y);
  res[2] = (_Float16)(w0 * a1.x + w1 * b1.x);
  res[3] = (_Float16)(w0 * a1.y + w1 * b1.y);
  int bb = n >> 4, h = n & 15;
  *(f16x4*)(attf + ((size_t)bb * L_SEQ + l) * 1024 + h * 64 + q4 * 4) = res;
}

extern "C" void kernel_launch(void* const* d_in, const int* in_sizes, int n_in,
                              void* d_out, int out_size, void* d_ws, size_t ws_size,
                              hipStream_t stream) {
  const float* x   = (const float*)d_in[0];
  const float* Wqk = (const float*)d_in[2];
  const float* Wv  = (const float*)d_in[3];
  const float* Wo  = (const float*)d_in[4];
  const float* rot = (const float*)d_in[5];
  float* out = (float*)d_out;
  char* ws = (char*)d_ws;

  _Float16*     qkh    = (_Float16*)(ws + 0);                 // 16 MB
  _Float16*     vh     = (_Float16*)(ws + 16777216ull);       // 16 MB
  _Float16*     xh     = (_Float16*)(ws + 33554432ull);       // 16 MB (dead after gemms)
  _Float16*     attf   = (_Float16*)(ws + 33554432ull);       // overlays xh
  _Float16*     o      = (_Float16*)(ws + 50331648ull);       // 32 MB (attn output)
  // pre-attn scratch overlaying the o region:
  unsigned int* lists  = (unsigned int*)(ws + 52428800ull);   // 512 KB (16 lists)
  unsigned int* cntp   = (unsigned int*)(ws + 53477376ull);   // 64 B
  float*        logits = (float*)(ws + 83886080ull);          // 1 MB
  unsigned int* st     = (unsigned int*)(ws + 84934656ull);   // 1 MB
  unsigned char* bucket = (unsigned char*)(ws + 85983232ull); // 256 KB
  _Float16*     WqkT   = (_Float16*)(ws + 86245376ull);       // 2 MB
  _Float16*     WvT    = (_Float16*)(ws + 88342528ull);       // 2 MB
  _Float16*     WoT    = (_Float16*)(ws + 90439680ull);       // 2 MB

  dim3 gb(256);
  dim3 gemmGrid(512);

  hipMemsetAsync(cntp, 0, 16 * sizeof(unsigned int), stream);
  cvt_f16<<<dim3(8192), gb, 0, stream>>>(x, xh);
  cvt_tr_f16<<<dim3(32, 32), gb, 0, stream>>>(Wqk, WqkT);
  cvt_tr_f16<<<dim3(32, 32), gb, 0, stream>>>(Wv, WvT);
  cvt_tr_f16<<<dim3(32, 32), gb, 0, stream>>>(Wo, WoT);

  gemm_f16<1><<<gemmGrid, gb, 0, stream>>>(xh, WqkT, (float*)qkh, 8192, 1024, 1024);
  gemm_f16<1><<<gemmGrid, gb, 0, stream>>>(xh, WvT, (float*)vh, 8192, 1024, 1024);

  lsh_hash2<<<dim3(16, 32), gb, 0, stream>>>(qkh, rot, bucket, lists, cntp);
  lsh_fixup4<<<dim3(512), gb, 0, stream>>>(x, Wqk, rot, lists, cntp, bucket);
  lsh_sort<<<dim3(64), gb, 0, stream>>>(bucket, st);
  lsh_attn_mfma<<<dim3(128, 32), gb, 0, stream>>>(qkh, vh, st, o, logits);
  lsh_combine<<<dim3(8192), gb, 0, stream>>>((const __half*)o, logits, attf);

  gemm_f16<0><<<gemmGrid, gb, 0, stream>>>(attf, WoT, out, 8192, 1024, 1024);
}

// Round 11
// 290.375 us; speedup vs baseline: 1.3089x; 1.0178x over previous
//
#include <hip/hip_runtime.h>
#include <hip/hip_fp16.h>

#define L_SEQ 4096
#define THR_GAP 0.08f
#define FIX_CAP 2048

typedef _Float16 f16x8 __attribute__((ext_vector_type(8)));
typedef _Float16 f16x4 __attribute__((ext_vector_type(4)));
typedef float f32x4 __attribute__((ext_vector_type(4)));

typedef __attribute__((address_space(3))) void lds_void;
typedef __attribute__((address_space(1))) void glob_void;
__device__ __forceinline__ void gload16(const _Float16* g, _Float16* l) {
  __builtin_amdgcn_global_load_lds((const glob_void*)g, (lds_void*)l, 16, 0, 0);
}

// ---------------- converts ----------------
__global__ __launch_bounds__(256)
void cvt_f16(const float* __restrict__ in, _Float16* __restrict__ out_) {
  int i = blockIdx.x * 256 + threadIdx.x;
  float4 v = ((const float4*)in)[i];
  f16x4 h;
  h[0] = (_Float16)v.x; h[1] = (_Float16)v.y;
  h[2] = (_Float16)v.z; h[3] = (_Float16)v.w;
  *(f16x4*)(out_ + (size_t)i * 4) = h;
}

__global__ __launch_bounds__(256)
void cvt_tr_f16(const float* __restrict__ W, _Float16* __restrict__ WT) {
  __shared__ _Float16 tile[32][33];
  const int bx = blockIdx.x * 32, by = blockIdx.y * 32;
  const int tx = threadIdx.x & 31, ty = threadIdx.x >> 5;
  #pragma unroll
  for (int i = ty; i < 32; i += 8)
    tile[i][tx] = (_Float16)W[(size_t)(by + i) * 1024 + bx + tx];
  __syncthreads();
  #pragma unroll
  for (int i = ty; i < 32; i += 8)
    WT[(size_t)(bx + i) * 1024 + by + tx] = tile[tx][i];
}

// ---------------- f16 MFMA GEMM, dbuf + counted vmcnt: C = A * BT^T ----------------
// MODE 0: C row-major f32; MODE 1: scatter f16 to [n][l][d]
template<int MODE>
__global__ __launch_bounds__(256)
void gemm_f16(const _Float16* __restrict__ A, const _Float16* __restrict__ BT,
              float* __restrict__ C, int M, int K, int Nn) {
  __shared__ _Float16 As[2][128 * 64];
  __shared__ _Float16 Bs[2][128 * 64];
  const int tid = threadIdx.x;
  const int lane = tid & 63, wid = tid >> 6;
  const int wr = wid >> 1, wc = wid & 1;
  const int f = blockIdx.x;
  const int u = (f & 7) * 64 + (f >> 3);
  const int row0 = (u >> 3) * 128, col0 = (u & 7) * 128;

  f32x4 acc[4][4];
  #pragma unroll
  for (int i = 0; i < 4; ++i)
    #pragma unroll
    for (int j = 0; j < 4; ++j)
      acc[i][j] = (f32x4){0.f, 0.f, 0.f, 0.f};

  const int srow = (lane >> 3);
  const int scol = ((lane & 7) ^ srow) * 8;
  const _Float16* ga = A + (size_t)(row0 + wid * 32 + srow) * K + scol;
  const _Float16* gb = BT + (size_t)(col0 + wid * 32 + srow) * K + scol;
  const int lbase = (wid * 32) * 64;
  const int fr = lane & 15, g = lane >> 4;

#define STAGE_F16(buf, k0) do {                                          \
    _Pragma("unroll")                                                    \
    for (int i_ = 0; i_ < 4; ++i_) {                                     \
      gload16(ga + (k0) + (size_t)i_ * 8 * K, &As[buf][lbase + i_ * 8 * 64]); \
      gload16(gb + (k0) + (size_t)i_ * 8 * K, &Bs[buf][lbase + i_ * 8 * 64]); \
    }                                                                    \
  } while (0)

  STAGE_F16(0, 0);

  const int NT = K / 64;
  for (int t = 0; t < NT; ++t) {
    const int cur = t & 1, nxt = cur ^ 1;
    if (t + 1 < NT) {
      STAGE_F16(nxt, (size_t)(t + 1) * 64);
      asm volatile("s_waitcnt vmcnt(8)" ::: "memory");
    } else {
      asm volatile("s_waitcnt vmcnt(0)" ::: "memory");
    }
    __builtin_amdgcn_s_barrier();
    __builtin_amdgcn_sched_barrier(0);

    f16x8 af[4][2], bf[4][2];
    #pragma unroll
    for (int fi = 0; fi < 4; ++fi) {
      const int ra = (wr * 64 + fi * 16 + fr) * 64;
      const int rb = (wc * 64 + fi * 16 + fr) * 64;
      #pragma unroll
      for (int ks = 0; ks < 2; ++ks) {
        const int ko = (ks * 32 + g * 8) ^ ((fr & 7) * 8);
        af[fi][ks] = *(const f16x8*)(&As[cur][ra + ko]);
        bf[fi][ks] = *(const f16x8*)(&Bs[cur][rb + ko]);
      }
    }
    #pragma unroll
    for (int ks = 0; ks < 2; ++ks)
      #pragma unroll
      for (int fi = 0; fi < 4; ++fi)
        #pragma unroll
        for (int fj = 0; fj < 4; ++fj)
          acc[fi][fj] = __builtin_amdgcn_mfma_f32_16x16x32_f16(
              af[fi][ks], bf[fj][ks], acc[fi][fj], 0, 0, 0);
    __builtin_amdgcn_s_barrier();
    __builtin_amdgcn_sched_barrier(0);
  }
#undef STAGE_F16

  _Float16* Ch = (_Float16*)C;
  #pragma unroll
  for (int fi = 0; fi < 4; ++fi) {
    #pragma unroll
    for (int fj = 0; fj < 4; ++fj) {
      const int col = col0 + wc * 64 + fj * 16 + fr;
      #pragma unroll
      for (int r = 0; r < 4; ++r) {
        const int row = row0 + wr * 64 + fi * 16 + g * 4 + r;
        if (MODE == 0) {
          C[(size_t)row * Nn + col] = acc[fi][fj][r];
        } else {
          int b = row >> 12, l = row & 4095;
          int h = col >> 6, d = col & 63;
          Ch[(((size_t)(b * 16 + h) * L_SEQ) + l) * 64 + d] = (_Float16)acc[fi][fj][r];
        }
      }
    }
  }
}

// ---------------- LSH hashing from f16 qk + per-(n,l) ambiguity flagging ----------------
__global__ __launch_bounds__(256)
void lsh_hash2(const _Float16* __restrict__ qkh, const float* __restrict__ rot,
               unsigned char* __restrict__ bucket,
               unsigned int* __restrict__ lists, unsigned int* __restrict__ cnt) {
  __shared__ float rots[4096];
  const int tid = threadIdx.x;
  for (int idx = tid; idx < 4096; idx += 256) rots[idx] = rot[idx];
  __syncthreads();
  const int n = blockIdx.y;
  const int l = blockIdx.x * 256 + tid;
  const f16x8* qp = (const f16x8*)(qkh + ((size_t)n * L_SEQ + l) * 64);
  float qr[64];
  #pragma unroll
  for (int t8 = 0; t8 < 8; ++t8) {
    f16x8 v = qp[t8];
    #pragma unroll
    for (int e = 0; e < 8; ++e) qr[t8 * 8 + e] = (float)v[e];
  }
  float gmin = 3.0e38f;
  #pragma unroll 1
  for (int hr = 0; hr < 2; ++hr) {
    float val[32];
    #pragma unroll
    for (int rb = 0; rb < 32; ++rb) val[rb] = 0.f;
    #pragma unroll
    for (int d = 0; d < 64; ++d) {
      float qd = qr[d];
      const float* rp = &rots[d * 64 + hr * 32];
      #pragma unroll
      for (int rb = 0; rb < 32; ++rb) val[rb] += qd * rp[rb];
    }
    float m1 = val[0]; int bi = 0;
    #pragma unroll
    for (int k = 1; k < 32; ++k) { if (val[k] > m1) { m1 = val[k]; bi = k; } }
    #pragma unroll
    for (int k = 0; k < 32; ++k) { float vn = -val[k]; if (vn > m1) { m1 = vn; bi = 32 + k; } }
    float m2 = -3.0e38f;
    #pragma unroll
    for (int k = 0; k < 32; ++k) { if (k != bi) m2 = fmaxf(m2, val[k]); }
    #pragma unroll
    for (int k = 0; k < 32; ++k) { if (32 + k != bi) m2 = fmaxf(m2, -val[k]); }
    bucket[((size_t)n * 2 + hr) * L_SEQ + l] = (unsigned char)bi;
    gmin = fminf(gmin, m1 - m2);
  }
  if (gmin < THR_GAP) {
    int h = n & 15;
    unsigned int pos = atomicAdd(&cnt[h], 1u);
    if (pos < FIX_CAP)
      lists[(size_t)h * FIX_CAP + pos] = ((unsigned int)n << 12) | (unsigned int)l;
  }
}

// ---------------- fixup phase A: per-head skinny GEMM qkfix = x_rows * Wqk_h -------
// block = (head, 64-item row tile); 64x64 tile, K=1024, BK=32
__global__ __launch_bounds__(256)
void lsh_fix_gemm(const float* __restrict__ x, const float* __restrict__ Wqk,
                  const unsigned int* __restrict__ lists,
                  const unsigned int* __restrict__ cnt,
                  float* __restrict__ qkfix) {
  __shared__ float As[32][65];
  __shared__ float Bs[32][64];
  __shared__ int rowIdx[64];
  const int h = blockIdx.x;
  const int rt = blockIdx.y;
  const unsigned int nfix = min(cnt[h], (unsigned int)FIX_CAP);
  if ((unsigned int)(rt * 64) >= nfix) return;
  const int tid = threadIdx.x;
  if (tid < 64) {
    unsigned int i = (unsigned int)(rt * 64 + tid);
    if (i >= nfix) i = nfix - 1;
    unsigned int ent = lists[(size_t)h * FIX_CAP + i];
    rowIdx[tid] = (int)((ent >> 12) >> 4) * 4096 + (int)(ent & 4095);
  }
  __syncthreads();
  float acc[4][4] = {{0.f}};
  const int tx = tid & 15, ty = tid >> 4;
  const int am = tid >> 2, ae = (tid & 3) * 8;
  const int be = tid >> 3, bd = (tid & 7) * 8;
  const size_t arow = (size_t)rowIdx[am] * 1024;
  for (int k0 = 0; k0 < 1024; k0 += 32) {
    {
      const float* xr = x + arow + k0 + ae;
      float4 v0 = *(const float4*)xr;
      float4 v1 = *(const float4*)(xr + 4);
      As[ae + 0][am] = v0.x; As[ae + 1][am] = v0.y;
      As[ae + 2][am] = v0.z; As[ae + 3][am] = v0.w;
      As[ae + 4][am] = v1.x; As[ae + 5][am] = v1.y;
      As[ae + 6][am] = v1.z; As[ae + 7][am] = v1.w;
    }
    {
      const float* wr = Wqk + (size_t)(k0 + be) * 1024 + h * 64 + bd;
      *(float4*)&Bs[be][bd] = *(const float4*)wr;
      *(float4*)&Bs[be][bd + 4] = *(const float4*)(wr + 4);
    }
    __syncthreads();
    #pragma unroll
    for (int k = 0; k < 32; ++k) {
      float a[4], b[4];
      #pragma unroll
      for (int j = 0; j < 4; ++j) a[j] = As[k][ty * 4 + j];
      #pragma unroll
      for (int j = 0; j < 4; ++j) b[j] = Bs[k][tx * 4 + j];
      #pragma unroll
      for (int i = 0; i < 4; ++i)
        #pragma unroll
        for (int j = 0; j < 4; ++j)
          acc[i][j] += a[i] * b[j];
    }
    __syncthreads();
  }
  #pragma unroll
  for (int i = 0; i < 4; ++i) {
    int m = rt * 64 + ty * 4 + i;   // duplicates past nfix are harmless
    float* dst = qkfix + ((size_t)h * FIX_CAP + m) * 64 + tx * 4;
    dst[0] = acc[i][0]; dst[1] = acc[i][1];
    dst[2] = acc[i][2]; dst[3] = acc[i][3];
  }
}

// ---------------- fixup phase B: rotations + exact argmax per item ----------------
__global__ __launch_bounds__(256)
void lsh_fix_rot(const float* __restrict__ qkfix, const float* __restrict__ rot,
                 const unsigned int* __restrict__ lists,
                 const unsigned int* __restrict__ cnt,
                 unsigned char* __restrict__ bucket) {
  __shared__ float rotL[4096];
  __shared__ float qkL[4][64];
  const int h = blockIdx.x & 15;
  const int bg = blockIdx.x >> 4;     // 0..15
  const int tid = threadIdx.x, lane = tid & 63, wv = tid >> 6;
  for (int i = tid; i < 4096; i += 256) rotL[i] = rot[i];
  __syncthreads();
  const unsigned int nfix = min(cnt[h], (unsigned int)FIX_CAP);
  for (unsigned int i = (unsigned int)(bg * 4 + wv); i < nfix; i += 64) {
    unsigned int ent = lists[(size_t)h * FIX_CAP + i];
    const int nn = (int)(ent >> 12), ll = (int)(ent & 4095);
    qkL[wv][lane] = qkfix[((size_t)h * FIX_CAP + i) * 64 + lane];
    asm volatile("s_waitcnt vmcnt(0) lgkmcnt(0)" ::: "memory");
    float v = 0.f;
    #pragma unroll 16
    for (int d = 0; d < 64; ++d)
      v += qkL[wv][d] * rotL[d * 64 + lane];
    const int r = lane & 31;
    float vneg = -v;
    float bv; int bi;
    if (vneg > v) { bv = vneg; bi = 32 + r; } else { bv = v; bi = r; }
    #pragma unroll
    for (int off = 1; off < 32; off <<= 1) {
      float ov = __shfl_xor(bv, off, 64);
      int oi = __shfl_xor(bi, off, 64);
      if (ov > bv || (ov == bv && oi < bi)) { bv = ov; bi = oi; }
    }
    if (r == 0) {
      int hr = lane >> 5;
      bucket[((size_t)(nn * 2 + hr)) * L_SEQ + ll] = (unsigned char)bi;
    }
  }
}

// ---------------- parallel stable counting sort per (n, round) ----------------
__global__ __launch_bounds__(256)
void lsh_sort(const unsigned char* __restrict__ bucket, unsigned int* __restrict__ st) {
  __shared__ unsigned short cnt[64][257];
  __shared__ unsigned int bstart[64];
  __shared__ unsigned char bkt[4096];
  const int nr = blockIdx.x;
  const int tid = threadIdx.x;
  const unsigned char* bsrc = bucket + (size_t)nr * L_SEQ;
  for (int i = tid; i < 1024; i += 256)
    ((unsigned int*)bkt)[i] = ((const unsigned int*)bsrc)[i];
  #pragma unroll
  for (int b = 0; b < 64; ++b) cnt[b][tid] = 0;
  __syncthreads();
  uint4 wv = ((const uint4*)bkt)[tid];
  unsigned int wsg[4] = {wv.x, wv.y, wv.z, wv.w};
  #pragma unroll
  for (int k = 0; k < 16; ++k) {
    int b = (wsg[k >> 2] >> ((k & 3) * 8)) & 63;
    cnt[b][tid]++;
  }
  __syncthreads();
  if (tid < 64) {
    const int b = tid;
    unsigned int run = 0;
    for (int t = 0; t < 256; ++t) {
      unsigned int c = cnt[b][t];
      cnt[b][t] = (unsigned short)run;
      run += c;
    }
    unsigned int incl = run;
    #pragma unroll
    for (int off = 1; off < 64; off <<= 1) {
      unsigned int up = (unsigned int)__shfl_up((int)incl, off);
      if (tid >= off) incl += up;
    }
    bstart[b] = incl - run;
  }
  __syncthreads();
  const int n = nr >> 1, r = nr & 1;
  unsigned int* dst = st + (size_t)n * 8192 + (size_t)r * 4096;
  #pragma unroll
  for (int k = 0; k < 16; ++k) {
    int b = (wsg[k >> 2] >> ((k & 3) * 8)) & 63;
    unsigned int idx = bstart[b] + cnt[b][tid];
    cnt[b][tid]++;
    dst[idx] = (unsigned int)(tid * 16 + k);
  }
}

// ---------------- MFMA chunked local attention (f16 qk gather) ----------------
__global__ __launch_bounds__(256)
void lsh_attn_mfma(const _Float16* __restrict__ qkh, const _Float16* __restrict__ vh,
                   const unsigned int* __restrict__ st,
                   _Float16* __restrict__ o, float* __restrict__ logits) {
  __shared__ _Float16 Kl[128 * 64];
  __shared__ _Float16 Vt[64 * 128];
  __shared__ _Float16 Pl[64 * 128];
  __shared__ float rsqs[128];
  __shared__ float partial[256];
  __shared__ int posl[128];

  const int tid = threadIdx.x;
  const int lane = tid & 63, wid = tid >> 6;
  const int fr = lane & 15, g = lane >> 4;
  const int c = blockIdx.x, n = blockIdx.y;
  const int cprev = (c + 127) & 127;

  if (tid < 128) {
    int p = (tid < 64) ? (c * 64 + tid) : (cprev * 64 + (tid - 64));
    posl[tid] = (int)st[(size_t)n * 8192 + p];
  }
  __syncthreads();

  {
    const int j = tid >> 1, h = tid & 1;
    const int gpos = posl[j];
    const f16x8* srcK = (const f16x8*)(qkh + ((size_t)n * L_SEQ + gpos) * 64 + h * 32);
    const f16x8* srcV = (const f16x8*)(vh + ((size_t)n * L_SEQ + gpos) * 64 + h * 32);
    float ss = 0.f;
    #pragma unroll
    for (int i = 0; i < 4; ++i) {
      f16x8 kv = srcK[i];
      f16x8 vv4 = srcV[i];
      #pragma unroll
      for (int e = 0; e < 8; ++e) {
        float xv = (float)kv[e];
        ss += xv * xv;
        int d = h * 32 + i * 8 + e;
        Vt[d * 128 + (j ^ ((d & 7) << 3))] = vv4[e];
      }
      int ch = h * 4 + i;
      *(f16x8*)(&Kl[j * 64 + ((ch ^ (j & 7)) * 8)]) = kv;
    }
    partial[tid] = ss;
  }
  __syncthreads();
  if (tid < 128)
    rsqs[tid] = rsqrtf(fmaxf(partial[tid * 2] + partial[tid * 2 + 1], 1e-12f));
  __syncthreads();

  const int q0 = wid * 16;
  f32x4 acc[8];
  #pragma unroll
  for (int t = 0; t < 8; ++t) acc[t] = (f32x4){0.f, 0.f, 0.f, 0.f};
  f16x8 aq[2];
  #pragma unroll
  for (int ks = 0; ks < 2; ++ks)
    aq[ks] = *(const f16x8*)&Kl[(q0 + fr) * 64 + (((ks * 4 + g) ^ (fr & 7)) * 8)];
  #pragma unroll
  for (int t = 0; t < 8; ++t) {
    #pragma unroll
    for (int ks = 0; ks < 2; ++ks) {
      f16x8 bk = *(const f16x8*)&Kl[(t * 16 + fr) * 64 + (((ks * 4 + g) ^ (fr & 7)) * 8)];
      acc[t] = __builtin_amdgcn_mfma_f32_16x16x32_f16(aq[ks], bk, acc[t], 0, 0, 0);
    }
  }

  float sc[8][4];
  int pq[4];
  #pragma unroll
  for (int r = 0; r < 4; ++r) pq[r] = posl[q0 + g * 4 + r];
  #pragma unroll
  for (int t = 0; t < 8; ++t) {
    float rs = rsqs[t * 16 + fr] * 0.125f;
    int pk = posl[t * 16 + fr];
    #pragma unroll
    for (int r = 0; r < 4; ++r) {
      float v_ = acc[t][r] * rs;
      if (pq[r] == pk) v_ += -1e5f;
      sc[t][r] = v_;
    }
  }
  float lsef[4];
  #pragma unroll
  for (int r = 0; r < 4; ++r) {
    float m = sc[0][r];
    #pragma unroll
    for (int t = 1; t < 8; ++t) m = fmaxf(m, sc[t][r]);
    #pragma unroll
    for (int off = 1; off < 16; off <<= 1) m = fmaxf(m, __shfl_xor(m, off, 64));
    float s = 0.f;
    #pragma unroll
    for (int t = 0; t < 8; ++t) { float e = __expf(sc[t][r] - m); sc[t][r] = e; s += e; }
    #pragma unroll
    for (int off = 1; off < 16; off <<= 1) s += __shfl_xor(s, off, 64);
    lsef[r] = m + __logf(s);
    float f = 1.0f / s;
    #pragma unroll
    for (int t = 0; t < 8; ++t) sc[t][r] *= f;
  }

  #pragma unroll
  for (int t = 0; t < 8; ++t)
    #pragma unroll
    for (int r = 0; r < 4; ++r) {
      int q = q0 + g * 4 + r;
      Pl[q * 128 + ((t * 16 + fr) ^ ((q & 7) << 3))] = (_Float16)sc[t][r];
    }
  const int rr = c >> 6;
  if (fr == 0) {
    #pragma unroll
    for (int r = 0; r < 4; ++r) {
      int q = q0 + g * 4 + r;
      logits[((size_t)n * 2 + rr) * L_SEQ + posl[q]] = lsef[r];
    }
  }

  f32x4 acc2[4];
  #pragma unroll
  for (int td = 0; td < 4; ++td) acc2[td] = (f32x4){0.f, 0.f, 0.f, 0.f};
  #pragma unroll
  for (int s = 0; s < 4; ++s) {
    f16x8 ap = *(const f16x8*)&Pl[(q0 + fr) * 128 + (((s * 4 + g) ^ (fr & 7)) * 8)];
    #pragma unroll
    for (int td = 0; td < 4; ++td) {
      f16x8 bv = *(const f16x8*)&Vt[(td * 16 + fr) * 128 + (((s * 4 + g) ^ (fr & 7)) * 8)];
      acc2[td] = __builtin_amdgcn_mfma_f32_16x16x32_f16(ap, bv, acc2[td], 0, 0, 0);
    }
  }
  #pragma unroll
  for (int r = 0; r < 4; ++r) {
    int q = q0 + g * 4 + r;
    size_t base = (((size_t)n * 2 + rr) * L_SEQ + posl[q]) * 64;
    #pragma unroll
    for (int td = 0; td < 4; ++td)
      o[base + td * 16 + fr] = (_Float16)acc2[td][r];
  }
}

// ---------------- combine hash rounds -> f16 att [8192][1024] ----------------
__global__ __launch_bounds__(256)
void lsh_combine(const __half* __restrict__ o, const float* __restrict__ logits,
                 _Float16* __restrict__ attf) {
  size_t gid = (size_t)blockIdx.x * 256 + threadIdx.x;
  int q4 = (int)(gid & 15);
  size_t nl = gid >> 4;
  int n = (int)(nl >> 12), l = (int)(nl & 4095);
  float l0 = logits[((size_t)n * 2 + 0) * L_SEQ + l];
  float l1 = logits[((size_t)n * 2 + 1) * L_SEQ + l];
  float m = fmaxf(l0, l1);
  float e0 = __expf(l0 - m), e1 = __expf(l1 - m);
  float inv = 1.0f / (e0 + e1);
  float w0 = e0 * inv, w1 = e1 * inv;
  const __half2* r0 = (const __half2*)(o + (((size_t)n * 2 + 0) * L_SEQ + l) * 64) + q4 * 2;
  const __half2* r1 = (const __half2*)(o + (((size_t)n * 2 + 1) * L_SEQ + l) * 64) + q4 * 2;
  float2 a0 = __half22float2(r0[0]), a1 = __half22float2(r0[1]);
  float2 b0 = __half22float2(r1[0]), b1 = __half22float2(r1[1]);
  f16x4 res;
  res[0] = (_Float16)(w0 * a0.x + w1 * b0.x);
  res[1] = (_Float16)(w0 * a0.y + w1 * b0.y);
  res[2] = (_Float16)(w0 * a1.x + w1 * b1.x);
  res[3] = (_Float16)(w0 * a1.y + w1 * b1.y);
  int bb = n >> 4, h = n & 15;
  *(f16x4*)(attf + ((size_t)bb * L_SEQ + l) * 1024 + h * 64 + q4 * 4) = res;
}

extern "C" void kernel_launch(void* const* d_in, const int* in_sizes, int n_in,
                              void* d_out, int out_size, void* d_ws, size_t ws_size,
                              hipStream_t stream) {
  const float* x   = (const float*)d_in[0];
  const float* Wqk = (const float*)d_in[2];
  const float* Wv  = (const float*)d_in[3];
  const float* Wo  = (const float*)d_in[4];
  const float* rot = (const float*)d_in[5];
  float* out = (float*)d_out;
  char* ws = (char*)d_ws;

  _Float16*     qkh    = (_Float16*)(ws + 0);                 // 16 MB
  _Float16*     vh     = (_Float16*)(ws + 16777216ull);       // 16 MB
  _Float16*     xh     = (_Float16*)(ws + 33554432ull);       // 16 MB (dead after gemms)
  _Float16*     attf   = (_Float16*)(ws + 33554432ull);       // overlays xh
  _Float16*     o      = (_Float16*)(ws + 50331648ull);       // 32 MB (attn output)
  // pre-attn fixup scratch overlaying the o region:
  unsigned int* lists  = (unsigned int*)(ws + 50331648ull);   // 128 KB (16 x 2048)
  unsigned int* cntp   = (unsigned int*)(ws + 50462720ull);   // 64 B
  float*        qkfix  = (float*)(ws + 51380224ull);          // 8 MB
  float*        logits = (float*)(ws + 83886080ull);          // 1 MB
  unsigned int* st     = (unsigned int*)(ws + 84934656ull);   // 1 MB
  unsigned char* bucket = (unsigned char*)(ws + 85983232ull); // 256 KB
  _Float16*     WqkT   = (_Float16*)(ws + 86245376ull);       // 2 MB
  _Float16*     WvT    = (_Float16*)(ws + 88342528ull);       // 2 MB
  _Float16*     WoT    = (_Float16*)(ws + 90439680ull);       // 2 MB

  dim3 gb(256);
  dim3 gemmGrid(512);

  hipMemsetAsync(cntp, 0, 16 * sizeof(unsigned int), stream);
  cvt_f16<<<dim3(8192), gb, 0, stream>>>(x, xh);
  cvt_tr_f16<<<dim3(32, 32), gb, 0, stream>>>(Wqk, WqkT);
  cvt_tr_f16<<<dim3(32, 32), gb, 0, stream>>>(Wv, WvT);
  cvt_tr_f16<<<dim3(32, 32), gb, 0, stream>>>(Wo, WoT);

  gemm_f16<1><<<gemmGrid, gb, 0, stream>>>(xh, WqkT, (float*)qkh, 8192, 1024, 1024);
  gemm_f16<1><<<gemmGrid, gb, 0, stream>>>(xh, WvT, (float*)vh, 8192, 1024, 1024);

  lsh_hash2<<<dim3(16, 32), gb, 0, stream>>>(qkh, rot, bucket, lists, cntp);
  lsh_fix_gemm<<<dim3(16, 32), gb, 0, stream>>>(x, Wqk, lists, cntp, qkfix);
  lsh_fix_rot<<<dim3(256), gb, 0, stream>>>(qkfix, rot, lists, cntp, bucket);
  lsh_sort<<<dim3(64), gb, 0, stream>>>(bucket, st);
  lsh_attn_mfma<<<dim3(128, 32), gb, 0, stream>>>(qkh, vh, st, o, logits);
  lsh_combine<<<dim3(8192), gb, 0, stream>>>((const __half*)o, logits, attf);

  gemm_f16<0><<<gemmGrid, gb, 0, stream>>>(attf, WoT, out, 8192, 1024, 1024);
}

// Round 12
// 241.919 us; speedup vs baseline: 1.5711x; 1.2003x over previous
//
#include <hip/hip_runtime.h>
#include <hip/hip_fp16.h>

#define L_SEQ 4096
#define THR_GAP 0.08f
#define FIX_CAP 1536

typedef _Float16 f16x8 __attribute__((ext_vector_type(8)));
typedef _Float16 f16x4 __attribute__((ext_vector_type(4)));
typedef float f32x4 __attribute__((ext_vector_type(4)));

typedef __attribute__((address_space(3))) void lds_void;
typedef __attribute__((address_space(1))) void glob_void;
__device__ __forceinline__ void gload16(const _Float16* g, _Float16* l) {
  __builtin_amdgcn_global_load_lds((const glob_void*)g, (lds_void*)l, 16, 0, 0);
}

// ---------------- converts ----------------
__global__ __launch_bounds__(256)
void cvt_f16(const float* __restrict__ in, _Float16* __restrict__ out_) {
  int i = blockIdx.x * 256 + threadIdx.x;
  float4 v = ((const float4*)in)[i];
  f16x4 h;
  h[0] = (_Float16)v.x; h[1] = (_Float16)v.y;
  h[2] = (_Float16)v.z; h[3] = (_Float16)v.w;
  *(f16x4*)(out_ + (size_t)i * 4) = h;
}

__global__ __launch_bounds__(256)
void cvt_tr_f16(const float* __restrict__ W, _Float16* __restrict__ WT) {
  __shared__ _Float16 tile[32][33];
  const int bx = blockIdx.x * 32, by = blockIdx.y * 32;
  const int tx = threadIdx.x & 31, ty = threadIdx.x >> 5;
  #pragma unroll
  for (int i = ty; i < 32; i += 8)
    tile[i][tx] = (_Float16)W[(size_t)(by + i) * 1024 + bx + tx];
  __syncthreads();
  #pragma unroll
  for (int i = ty; i < 32; i += 8)
    WT[(size_t)(bx + i) * 1024 + by + tx] = tile[tx][i];
}

// ---------------- f16 MFMA GEMM, dbuf + counted vmcnt: C = A * BT^T ----------------
// MODE 0: C row-major f32; MODE 1: scatter f16 to [n][l][d]
template<int MODE>
__global__ __launch_bounds__(256)
void gemm_f16(const _Float16* __restrict__ A, const _Float16* __restrict__ BT,
              float* __restrict__ C, int M, int K, int Nn) {
  __shared__ _Float16 As[2][128 * 64];
  __shared__ _Float16 Bs[2][128 * 64];
  const int tid = threadIdx.x;
  const int lane = tid & 63, wid = tid >> 6;
  const int wr = wid >> 1, wc = wid & 1;
  const int f = blockIdx.x;
  const int u = (f & 7) * 64 + (f >> 3);
  const int row0 = (u >> 3) * 128, col0 = (u & 7) * 128;

  f32x4 acc[4][4];
  #pragma unroll
  for (int i = 0; i < 4; ++i)
    #pragma unroll
    for (int j = 0; j < 4; ++j)
      acc[i][j] = (f32x4){0.f, 0.f, 0.f, 0.f};

  const int srow = (lane >> 3);
  const int scol = ((lane & 7) ^ srow) * 8;
  const _Float16* ga = A + (size_t)(row0 + wid * 32 + srow) * K + scol;
  const _Float16* gb = BT + (size_t)(col0 + wid * 32 + srow) * K + scol;
  const int lbase = (wid * 32) * 64;
  const int fr = lane & 15, g = lane >> 4;

#define STAGE_F16(buf, k0) do {                                          \
    _Pragma("unroll")                                                    \
    for (int i_ = 0; i_ < 4; ++i_) {                                     \
      gload16(ga + (k0) + (size_t)i_ * 8 * K, &As[buf][lbase + i_ * 8 * 64]); \
      gload16(gb + (k0) + (size_t)i_ * 8 * K, &Bs[buf][lbase + i_ * 8 * 64]); \
    }                                                                    \
  } while (0)

  STAGE_F16(0, 0);

  const int NT = K / 64;
  for (int t = 0; t < NT; ++t) {
    const int cur = t & 1, nxt = cur ^ 1;
    if (t + 1 < NT) {
      STAGE_F16(nxt, (size_t)(t + 1) * 64);
      asm volatile("s_waitcnt vmcnt(8)" ::: "memory");
    } else {
      asm volatile("s_waitcnt vmcnt(0)" ::: "memory");
    }
    __builtin_amdgcn_s_barrier();
    __builtin_amdgcn_sched_barrier(0);

    f16x8 af[4][2], bf[4][2];
    #pragma unroll
    for (int fi = 0; fi < 4; ++fi) {
      const int ra = (wr * 64 + fi * 16 + fr) * 64;
      const int rb = (wc * 64 + fi * 16 + fr) * 64;
      #pragma unroll
      for (int ks = 0; ks < 2; ++ks) {
        const int ko = (ks * 32 + g * 8) ^ ((fr & 7) * 8);
        af[fi][ks] = *(const f16x8*)(&As[cur][ra + ko]);
        bf[fi][ks] = *(const f16x8*)(&Bs[cur][rb + ko]);
      }
    }
    #pragma unroll
    for (int ks = 0; ks < 2; ++ks)
      #pragma unroll
      for (int fi = 0; fi < 4; ++fi)
        #pragma unroll
        for (int fj = 0; fj < 4; ++fj)
          acc[fi][fj] = __builtin_amdgcn_mfma_f32_16x16x32_f16(
              af[fi][ks], bf[fj][ks], acc[fi][fj], 0, 0, 0);
    __builtin_amdgcn_s_barrier();
    __builtin_amdgcn_sched_barrier(0);
  }
#undef STAGE_F16

  _Float16* Ch = (_Float16*)C;
  #pragma unroll
  for (int fi = 0; fi < 4; ++fi) {
    #pragma unroll
    for (int fj = 0; fj < 4; ++fj) {
      const int col = col0 + wc * 64 + fj * 16 + fr;
      #pragma unroll
      for (int r = 0; r < 4; ++r) {
        const int row = row0 + wr * 64 + fi * 16 + g * 4 + r;
        if (MODE == 0) {
          C[(size_t)row * Nn + col] = acc[fi][fj][r];
        } else {
          int b = row >> 12, l = row & 4095;
          int h = col >> 6, d = col & 63;
          Ch[(((size_t)(b * 16 + h) * L_SEQ) + l) * 64 + d] = (_Float16)acc[fi][fj][r];
        }
      }
    }
  }
}

// ---------------- LSH hashing from f16 qk + per-(n,l) ambiguity flagging ----------------
__global__ __launch_bounds__(256)
void lsh_hash2(const _Float16* __restrict__ qkh, const float* __restrict__ rot,
               unsigned char* __restrict__ bucket,
               unsigned int* __restrict__ lists, unsigned int* __restrict__ cnt) {
  __shared__ float rots[4096];
  const int tid = threadIdx.x;
  for (int idx = tid; idx < 4096; idx += 256) rots[idx] = rot[idx];
  __syncthreads();
  const int n = blockIdx.y;
  const int l = blockIdx.x * 256 + tid;
  const f16x8* qp = (const f16x8*)(qkh + ((size_t)n * L_SEQ + l) * 64);
  float qr[64];
  #pragma unroll
  for (int t8 = 0; t8 < 8; ++t8) {
    f16x8 v = qp[t8];
    #pragma unroll
    for (int e = 0; e < 8; ++e) qr[t8 * 8 + e] = (float)v[e];
  }
  float gmin = 3.0e38f;
  #pragma unroll 1
  for (int hr = 0; hr < 2; ++hr) {
    float val[32];
    #pragma unroll
    for (int rb = 0; rb < 32; ++rb) val[rb] = 0.f;
    #pragma unroll
    for (int d = 0; d < 64; ++d) {
      float qd = qr[d];
      const float* rp = &rots[d * 64 + hr * 32];
      #pragma unroll
      for (int rb = 0; rb < 32; ++rb) val[rb] += qd * rp[rb];
    }
    float m1 = val[0]; int bi = 0;
    #pragma unroll
    for (int k = 1; k < 32; ++k) { if (val[k] > m1) { m1 = val[k]; bi = k; } }
    #pragma unroll
    for (int k = 0; k < 32; ++k) { float vn = -val[k]; if (vn > m1) { m1 = vn; bi = 32 + k; } }
    float m2 = -3.0e38f;
    #pragma unroll
    for (int k = 0; k < 32; ++k) { if (k != bi) m2 = fmaxf(m2, val[k]); }
    #pragma unroll
    for (int k = 0; k < 32; ++k) { if (32 + k != bi) m2 = fmaxf(m2, -val[k]); }
    bucket[((size_t)n * 2 + hr) * L_SEQ + l] = (unsigned char)bi;
    gmin = fminf(gmin, m1 - m2);
  }
  if (gmin < THR_GAP) {
    int h = n & 15;
    unsigned int pos = atomicAdd(&cnt[h], 1u);
    if (pos < FIX_CAP)
      lists[(size_t)h * FIX_CAP + pos] = ((unsigned int)n << 12) | (unsigned int)l;
  }
}

// ---------------- fixup phase A: K-split skinny GEMM partials ----------------
// grid (head, row-tile, K-chunk); 64x64 tile, K-chunk=256, BK=32, reg-prefetch
__global__ __launch_bounds__(256)
void lsh_fix_gemm(const float* __restrict__ x, const float* __restrict__ Wqk,
                  const unsigned int* __restrict__ lists,
                  const unsigned int* __restrict__ cnt,
                  float* __restrict__ qkfixp) {
  __shared__ float As[32][65];
  __shared__ float Bs[32][64];
  __shared__ int rowIdx[64];
  const int h = blockIdx.x;
  const int rt = blockIdx.y;
  const int ks = blockIdx.z;
  const unsigned int nfix = min(cnt[h], (unsigned int)FIX_CAP);
  if ((unsigned int)(rt * 64) >= nfix) return;
  const int tid = threadIdx.x;
  if (tid < 64) {
    unsigned int i = (unsigned int)(rt * 64 + tid);
    if (i >= nfix) i = nfix - 1;
    unsigned int ent = lists[(size_t)h * FIX_CAP + i];
    rowIdx[tid] = (int)((ent >> 12) >> 4) * 4096 + (int)(ent & 4095);
  }
  __syncthreads();
  float acc[4][4] = {{0.f}};
  const int tx = tid & 15, ty = tid >> 4;
  const int am = tid >> 2, ae = (tid & 3) * 8;
  const int be = tid >> 3, bd = (tid & 7) * 8;
  const size_t arow = (size_t)rowIdx[am] * 1024;
  const int kbeg = ks * 256, kend = kbeg + 256;

  float4 ra0, ra1, rb0, rb1;
  {
    const float* xr = x + arow + kbeg + ae;
    ra0 = *(const float4*)xr; ra1 = *(const float4*)(xr + 4);
    const float* wr = Wqk + (size_t)(kbeg + be) * 1024 + h * 64 + bd;
    rb0 = *(const float4*)wr; rb1 = *(const float4*)(wr + 4);
  }
  for (int k0 = kbeg; k0 < kend; k0 += 32) {
    As[ae + 0][am] = ra0.x; As[ae + 1][am] = ra0.y;
    As[ae + 2][am] = ra0.z; As[ae + 3][am] = ra0.w;
    As[ae + 4][am] = ra1.x; As[ae + 5][am] = ra1.y;
    As[ae + 6][am] = ra1.z; As[ae + 7][am] = ra1.w;
    *(float4*)&Bs[be][bd] = rb0;
    *(float4*)&Bs[be][bd + 4] = rb1;
    __syncthreads();
    if (k0 + 32 < kend) {   // prefetch next tile while computing current
      const float* xr = x + arow + (k0 + 32) + ae;
      ra0 = *(const float4*)xr; ra1 = *(const float4*)(xr + 4);
      const float* wr = Wqk + (size_t)(k0 + 32 + be) * 1024 + h * 64 + bd;
      rb0 = *(const float4*)wr; rb1 = *(const float4*)(wr + 4);
    }
    #pragma unroll
    for (int k = 0; k < 32; ++k) {
      float a[4], b[4];
      #pragma unroll
      for (int j = 0; j < 4; ++j) a[j] = As[k][ty * 4 + j];
      #pragma unroll
      for (int j = 0; j < 4; ++j) b[j] = Bs[k][tx * 4 + j];
      #pragma unroll
      for (int i = 0; i < 4; ++i)
        #pragma unroll
        for (int j = 0; j < 4; ++j)
          acc[i][j] += a[i] * b[j];
    }
    __syncthreads();
  }
  #pragma unroll
  for (int i = 0; i < 4; ++i) {
    int m = rt * 64 + ty * 4 + i;   // rows past nfix are dup-writes of same value
    float* dst = qkfixp + (((size_t)ks * 16 + h) * FIX_CAP + m) * 64 + tx * 4;
    dst[0] = acc[i][0]; dst[1] = acc[i][1];
    dst[2] = acc[i][2]; dst[3] = acc[i][3];
  }
}

// ---------------- fixup phase B: sum K-partials, rotations, exact argmax --------
__global__ __launch_bounds__(256)
void lsh_fix_rot(const float* __restrict__ qkfixp, const float* __restrict__ rot,
                 const unsigned int* __restrict__ lists,
                 const unsigned int* __restrict__ cnt,
                 unsigned char* __restrict__ bucket) {
  __shared__ float rotL[4096];
  __shared__ float qkL[4][64];
  const int h = blockIdx.x & 15;
  const int bg = blockIdx.x >> 4;     // 0..15
  const int tid = threadIdx.x, lane = tid & 63, wv = tid >> 6;
  for (int i = tid; i < 4096; i += 256) rotL[i] = rot[i];
  __syncthreads();
  const unsigned int nfix = min(cnt[h], (unsigned int)FIX_CAP);
  for (unsigned int i = (unsigned int)(bg * 4 + wv); i < nfix; i += 64) {
    unsigned int ent = lists[(size_t)h * FIX_CAP + i];
    const int nn = (int)(ent >> 12), ll = (int)(ent & 4095);
    // sum the 4 K-chunk partials in ascending-k order
    float s0 = qkfixp[(((size_t)0 * 16 + h) * FIX_CAP + i) * 64 + lane];
    float s1 = qkfixp[(((size_t)1 * 16 + h) * FIX_CAP + i) * 64 + lane];
    float s2 = qkfixp[(((size_t)2 * 16 + h) * FIX_CAP + i) * 64 + lane];
    float s3 = qkfixp[(((size_t)3 * 16 + h) * FIX_CAP + i) * 64 + lane];
    qkL[wv][lane] = ((s0 + s1) + s2) + s3;
    asm volatile("s_waitcnt vmcnt(0) lgkmcnt(0)" ::: "memory");
    float v = 0.f;
    #pragma unroll 16
    for (int d = 0; d < 64; ++d)
      v += qkL[wv][d] * rotL[d * 64 + lane];
    const int r = lane & 31;
    float vneg = -v;
    float bv; int bi;
    if (vneg > v) { bv = vneg; bi = 32 + r; } else { bv = v; bi = r; }
    #pragma unroll
    for (int off = 1; off < 32; off <<= 1) {
      float ov = __shfl_xor(bv, off, 64);
      int oi = __shfl_xor(bi, off, 64);
      if (ov > bv || (ov == bv && oi < bi)) { bv = ov; bi = oi; }
    }
    if (r == 0) {
      int hr = lane >> 5;
      bucket[((size_t)(nn * 2 + hr)) * L_SEQ + ll] = (unsigned char)bi;
    }
  }
}

// ---------------- parallel stable counting sort per (n, round) ----------------
__global__ __launch_bounds__(256)
void lsh_sort(const unsigned char* __restrict__ bucket, unsigned int* __restrict__ st) {
  __shared__ unsigned short cnt[64][257];
  __shared__ unsigned int bstart[64];
  __shared__ unsigned char bkt[4096];
  const int nr = blockIdx.x;
  const int tid = threadIdx.x;
  const unsigned char* bsrc = bucket + (size_t)nr * L_SEQ;
  for (int i = tid; i < 1024; i += 256)
    ((unsigned int*)bkt)[i] = ((const unsigned int*)bsrc)[i];
  #pragma unroll
  for (int b = 0; b < 64; ++b) cnt[b][tid] = 0;
  __syncthreads();
  uint4 wv = ((const uint4*)bkt)[tid];
  unsigned int wsg[4] = {wv.x, wv.y, wv.z, wv.w};
  #pragma unroll
  for (int k = 0; k < 16; ++k) {
    int b = (wsg[k >> 2] >> ((k & 3) * 8)) & 63;
    cnt[b][tid]++;
  }
  __syncthreads();
  if (tid < 64) {
    const int b = tid;
    unsigned int run = 0;
    for (int t = 0; t < 256; ++t) {
      unsigned int c = cnt[b][t];
      cnt[b][t] = (unsigned short)run;
      run += c;
    }
    unsigned int incl = run;
    #pragma unroll
    for (int off = 1; off < 64; off <<= 1) {
      unsigned int up = (unsigned int)__shfl_up((int)incl, off);
      if (tid >= off) incl += up;
    }
    bstart[b] = incl - run;
  }
  __syncthreads();
  const int n = nr >> 1, r = nr & 1;
  unsigned int* dst = st + (size_t)n * 8192 + (size_t)r * 4096;
  #pragma unroll
  for (int k = 0; k < 16; ++k) {
    int b = (wsg[k >> 2] >> ((k & 3) * 8)) & 63;
    unsigned int idx = bstart[b] + cnt[b][tid];
    cnt[b][tid]++;
    dst[idx] = (unsigned int)(tid * 16 + k);
  }
}

// ---------------- MFMA chunked local attention (f16 qk gather) ----------------
__global__ __launch_bounds__(256)
void lsh_attn_mfma(const _Float16* __restrict__ qkh, const _Float16* __restrict__ vh,
                   const unsigned int* __restrict__ st,
                   _Float16* __restrict__ o, float* __restrict__ logits) {
  __shared__ _Float16 Kl[128 * 64];
  __shared__ _Float16 Vt[64 * 128];
  __shared__ _Float16 Pl[64 * 128];
  __shared__ float rsqs[128];
  __shared__ float partial[256];
  __shared__ int posl[128];

  const int tid = threadIdx.x;
  const int lane = tid & 63, wid = tid >> 6;
  const int fr = lane & 15, g = lane >> 4;
  const int c = blockIdx.x, n = blockIdx.y;
  const int cprev = (c + 127) & 127;

  if (tid < 128) {
    int p = (tid < 64) ? (c * 64 + tid) : (cprev * 64 + (tid - 64));
    posl[tid] = (int)st[(size_t)n * 8192 + p];
  }
  __syncthreads();

  {
    const int j = tid >> 1, h = tid & 1;
    const int gpos = posl[j];
    const f16x8* srcK = (const f16x8*)(qkh + ((size_t)n * L_SEQ + gpos) * 64 + h * 32);
    const f16x8* srcV = (const f16x8*)(vh + ((size_t)n * L_SEQ + gpos) * 64 + h * 32);
    float ss = 0.f;
    #pragma unroll
    for (int i = 0; i < 4; ++i) {
      f16x8 kv = srcK[i];
      f16x8 vv4 = srcV[i];
      #pragma unroll
      for (int e = 0; e < 8; ++e) {
        float xv = (float)kv[e];
        ss += xv * xv;
        int d = h * 32 + i * 8 + e;
        Vt[d * 128 + (j ^ ((d & 7) << 3))] = vv4[e];
      }
      int ch = h * 4 + i;
      *(f16x8*)(&Kl[j * 64 + ((ch ^ (j & 7)) * 8)]) = kv;
    }
    partial[tid] = ss;
  }
  __syncthreads();
  if (tid < 128)
    rsqs[tid] = rsqrtf(fmaxf(partial[tid * 2] + partial[tid * 2 + 1], 1e-12f));
  __syncthreads();

  const int q0 = wid * 16;
  f32x4 acc[8];
  #pragma unroll
  for (int t = 0; t < 8; ++t) acc[t] = (f32x4){0.f, 0.f, 0.f, 0.f};
  f16x8 aq[2];
  #pragma unroll
  for (int ks = 0; ks < 2; ++ks)
    aq[ks] = *(const f16x8*)&Kl[(q0 + fr) * 64 + (((ks * 4 + g) ^ (fr & 7)) * 8)];
  #pragma unroll
  for (int t = 0; t < 8; ++t) {
    #pragma unroll
    for (int ks = 0; ks < 2; ++ks) {
      f16x8 bk = *(const f16x8*)&Kl[(t * 16 + fr) * 64 + (((ks * 4 + g) ^ (fr & 7)) * 8)];
      acc[t] = __builtin_amdgcn_mfma_f32_16x16x32_f16(aq[ks], bk, acc[t], 0, 0, 0);
    }
  }

  float sc[8][4];
  int pq[4];
  #pragma unroll
  for (int r = 0; r < 4; ++r) pq[r] = posl[q0 + g * 4 + r];
  #pragma unroll
  for (int t = 0; t < 8; ++t) {
    float rs = rsqs[t * 16 + fr] * 0.125f;
    int pk = posl[t * 16 + fr];
    #pragma unroll
    for (int r = 0; r < 4; ++r) {
      float v_ = acc[t][r] * rs;
      if (pq[r] == pk) v_ += -1e5f;
      sc[t][r] = v_;
    }
  }
  float lsef[4];
  #pragma unroll
  for (int r = 0; r < 4; ++r) {
    float m = sc[0][r];
    #pragma unroll
    for (int t = 1; t < 8; ++t) m = fmaxf(m, sc[t][r]);
    #pragma unroll
    for (int off = 1; off < 16; off <<= 1) m = fmaxf(m, __shfl_xor(m, off, 64));
    float s = 0.f;
    #pragma unroll
    for (int t = 0; t < 8; ++t) { float e = __expf(sc[t][r] - m); sc[t][r] = e; s += e; }
    #pragma unroll
    for (int off = 1; off < 16; off <<= 1) s += __shfl_xor(s, off, 64);
    lsef[r] = m + __logf(s);
    float f = 1.0f / s;
    #pragma unroll
    for (int t = 0; t < 8; ++t) sc[t][r] *= f;
  }

  #pragma unroll
  for (int t = 0; t < 8; ++t)
    #pragma unroll
    for (int r = 0; r < 4; ++r) {
      int q = q0 + g * 4 + r;
      Pl[q * 128 + ((t * 16 + fr) ^ ((q & 7) << 3))] = (_Float16)sc[t][r];
    }
  const int rr = c >> 6;
  if (fr == 0) {
    #pragma unroll
    for (int r = 0; r < 4; ++r) {
      int q = q0 + g * 4 + r;
      logits[((size_t)n * 2 + rr) * L_SEQ + posl[q]] = lsef[r];
    }
  }

  f32x4 acc2[4];
  #pragma unroll
  for (int td = 0; td < 4; ++td) acc2[td] = (f32x4){0.f, 0.f, 0.f, 0.f};
  #pragma unroll
  for (int s = 0; s < 4; ++s) {
    f16x8 ap = *(const f16x8*)&Pl[(q0 + fr) * 128 + (((s * 4 + g) ^ (fr & 7)) * 8)];
    #pragma unroll
    for (int td = 0; td < 4; ++td) {
      f16x8 bv = *(const f16x8*)&Vt[(td * 16 + fr) * 128 + (((s * 4 + g) ^ (fr & 7)) * 8)];
      acc2[td] = __builtin_amdgcn_mfma_f32_16x16x32_f16(ap, bv, acc2[td], 0, 0, 0);
    }
  }
  #pragma unroll
  for (int r = 0; r < 4; ++r) {
    int q = q0 + g * 4 + r;
    size_t base = (((size_t)n * 2 + rr) * L_SEQ + posl[q]) * 64;
    #pragma unroll
    for (int td = 0; td < 4; ++td)
      o[base + td * 16 + fr] = (_Float16)acc2[td][r];
  }
}

// ---------------- combine hash rounds -> f16 att [8192][1024] ----------------
__global__ __launch_bounds__(256)
void lsh_combine(const __half* __restrict__ o, const float* __restrict__ logits,
                 _Float16* __restrict__ attf) {
  size_t gid = (size_t)blockIdx.x * 256 + threadIdx.x;
  int q4 = (int)(gid & 15);
  size_t nl = gid >> 4;
  int n = (int)(nl >> 12), l = (int)(nl & 4095);
  float l0 = logits[((size_t)n * 2 + 0) * L_SEQ + l];
  float l1 = logits[((size_t)n * 2 + 1) * L_SEQ + l];
  float m = fmaxf(l0, l1);
  float e0 = __expf(l0 - m), e1 = __expf(l1 - m);
  float inv = 1.0f / (e0 + e1);
  float w0 = e0 * inv, w1 = e1 * inv;
  const __half2* r0 = (const __half2*)(o + (((size_t)n * 2 + 0) * L_SEQ + l) * 64) + q4 * 2;
  const __half2* r1 = (const __half2*)(o + (((size_t)n * 2 + 1) * L_SEQ + l) * 64) + q4 * 2;
  float2 a0 = __half22float2(r0[0]), a1 = __half22float2(r0[1]);
  float2 b0 = __half22float2(r1[0]), b1 = __half22float2(r1[1]);
  f16x4 res;
  res[0] = (_Float16)(w0 * a0.x + w1 * b0.x);
  res[1] = (_Float16)(w0 * a0.y + w1 * b0.y);
  res[2] = (_Float16)(w0 * a1.x + w1 * b1.x);
  res[3] = (_Float16)(w0 * a1.y + w1 * b1.y);
  int bb = n >> 4, h = n & 15;
  *(f16x4*)(attf + ((size_t)bb * L_SEQ + l) * 1024 + h * 64 + q4 * 4) = res;
}

extern "C" void kernel_launch(void* const* d_in, const int* in_sizes, int n_in,
                              void* d_out, int out_size, void* d_ws, size_t ws_size,
                              hipStream_t stream) {
  const float* x   = (const float*)d_in[0];
  const float* Wqk = (const float*)d_in[2];
  const float* Wv  = (const float*)d_in[3];
  const float* Wo  = (const float*)d_in[4];
  const float* rot = (const float*)d_in[5];
  float* out = (float*)d_out;
  char* ws = (char*)d_ws;

  _Float16*     qkh    = (_Float16*)(ws + 0);                 // 16 MB
  _Float16*     vh     = (_Float16*)(ws + 16777216ull);       // 16 MB
  _Float16*     xh     = (_Float16*)(ws + 33554432ull);       // 16 MB (dead after gemms)
  _Float16*     attf   = (_Float16*)(ws + 33554432ull);       // overlays xh
  _Float16*     o      = (_Float16*)(ws + 50331648ull);       // 32 MB (attn output)
  // pre-attn fixup scratch overlaying the o region:
  unsigned int* lists  = (unsigned int*)(ws + 50331648ull);   // 96 KB (16 x 1536)
  unsigned int* cntp   = (unsigned int*)(ws + 50429952ull);   // 64 B
  float*        qkfixp = (float*)(ws + 50528256ull);          // 24 MB (4 K-chunks)
  float*        logits = (float*)(ws + 83886080ull);          // 1 MB
  unsigned int* st     = (unsigned int*)(ws + 84934656ull);   // 1 MB
  unsigned char* bucket = (unsigned char*)(ws + 85983232ull); // 256 KB
  _Float16*     WqkT   = (_Float16*)(ws + 86245376ull);       // 2 MB
  _Float16*     WvT    = (_Float16*)(ws + 88342528ull);       // 2 MB
  _Float16*     WoT    = (_Float16*)(ws + 90439680ull);       // 2 MB

  dim3 gb(256);
  dim3 gemmGrid(512);

  hipMemsetAsync(cntp, 0, 16 * sizeof(unsigned int), stream);
  cvt_f16<<<dim3(8192), gb, 0, stream>>>(x, xh);
  cvt_tr_f16<<<dim3(32, 32), gb, 0, stream>>>(Wqk, WqkT);
  cvt_tr_f16<<<dim3(32, 32), gb, 0, stream>>>(Wv, WvT);
  cvt_tr_f16<<<dim3(32, 32), gb, 0, stream>>>(Wo, WoT);

  gemm_f16<1><<<gemmGrid, gb, 0, stream>>>(xh, WqkT, (float*)qkh, 8192, 1024, 1024);
  gemm_f16<1><<<gemmGrid, gb, 0, stream>>>(xh, WvT, (float*)vh, 8192, 1024, 1024);

  lsh_hash2<<<dim3(16, 32), gb, 0, stream>>>(qkh, rot, bucket, lists, cntp);
  lsh_fix_gemm<<<dim3(16, 24, 4), gb, 0, stream>>>(x, Wqk, lists, cntp, qkfixp);
  lsh_fix_rot<<<dim3(256), gb, 0, stream>>>(qkfixp, rot, lists, cntp, bucket);
  lsh_sort<<<dim3(64), gb, 0, stream>>>(bucket, st);
  lsh_attn_mfma<<<dim3(128, 32), gb, 0, stream>>>(qkh, vh, st, o, logits);
  lsh_combine<<<dim3(8192), gb, 0, stream>>>((const __half*)o, logits, attf);

  gemm_f16<0><<<gemmGrid, gb, 0, stream>>>(attf, WoT, out, 8192, 1024, 1024);
}